// Round 17
// baseline (1473.685 us; speedup 1.0000x reference)
//
#include <hip/hip_runtime.h>
#include <hip/hip_cooperative_groups.h>
#include <cstddef>

namespace cg = cooperative_groups;

#define NN 50000
#define EE 1600000
#define IN_DIM 512
#define HID 256
#define OUT_DIM 40
#define KSTEPS 10
#define BN_EPS 1e-5f

#define HB 256                 // histogram/scatter blocks
#define ECHUNK (EE / HB)       // 6250 edges per block
#define BNODE 40               // dest nodes per bucket
#define NB 1280                // buckets (covers 51200 >= NN)
#define HRW ((NN + 3) / 4)     // 12500 words of packed byte counts
#define SORTCAP 3072           // max edges per bucket (mean 1250)

#define PGRID 512              // cooperative grid: 2 blocks/CU, far below limit
#define GW (PGRID * 4)         // 2048 persistent waves

typedef __attribute__((ext_vector_type(8))) short short8;
typedef __attribute__((ext_vector_type(4))) float f32x4;

__device__ inline unsigned short bf16_rne(float v) {
    union { float f; unsigned u; } c; c.f = v;
    unsigned u = c.u;
    unsigned r = u + 0x7fff + ((u >> 16) & 1);
    return (unsigned short)(r >> 16);
}
__device__ inline float bf16_to_f(unsigned short h) {
    union { unsigned u; float f; } c; c.u = ((unsigned)h) << 16;
    return c.f;
}

// ---------------- phase 1: LDS histograms; histB stored TRANSPOSED [NB][HB] ----------------
__global__ __launch_bounds__(256) void k_hist(const int* __restrict__ ei,
                                              unsigned* __restrict__ histR8,
                                              int* __restrict__ histBT) {
    __shared__ unsigned hr[HRW];   // 50 KB
    __shared__ int hb[NB];         // 5 KB
    int b = blockIdx.x, tid = threadIdx.x;
    for (int i = tid; i < HRW; i += 256) hr[i] = 0;
    for (int i = tid; i < NB; i += 256) hb[i] = 0;
    __syncthreads();
    int e0 = b * ECHUNK;
    for (int e = e0 + tid; e < e0 + ECHUNK; e += 256) {
        int r = ei[e];
        int c = ei[EE + e];
        atomicAdd(&hr[r >> 2], 1u << ((r & 3) * 8));
        atomicAdd(&hb[(unsigned)c / BNODE], 1);
    }
    __syncthreads();
    unsigned* o = histR8 + (size_t)b * HRW;
    for (int i = tid; i < HRW; i += 256) o[i] = hr[i];
    for (int i = tid; i < NB; i += 256) histBT[(size_t)i * HB + b] = hb[i];
}

// ---------------- row-degree reduce -> dinv ----------------
__global__ void k_dinv2(const unsigned* __restrict__ histR8, float* __restrict__ dinv) {
    int i = blockIdx.x * blockDim.x + threadIdx.x;
    if (i >= NN) return;
    int word = i >> 2, sh = (i & 3) * 8;
    int d = 0;
    for (int blk = 0; blk < HB; ++blk)
        d += (histR8[(size_t)blk * HRW + word] >> sh) & 0xFFu;
    float fd = d < 1 ? 1.0f : (float)d;
    dinv[i] = 1.0f / sqrtf(fd);
}

// ---------------- per-bucket prefix across blocks: one WAVE per bucket ----------------
__global__ __launch_bounds__(256) void k_colsumB(int* __restrict__ histBT,
                                                 int* __restrict__ totB) {
    int wv = (blockIdx.x * 256 + threadIdx.x) >> 6;   // bucket
    int lane = threadIdx.x & 63;
    if (wv >= NB) return;
    int4 v = ((int4*)(histBT + (size_t)wv * HB))[lane];
    int s = v.x + v.y + v.z + v.w;
    int p = s;
    for (int d = 1; d < 64; d <<= 1) {
        int t = __shfl_up(p, d);
        if (lane >= d) p += t;
    }
    int excl = p - s;
    int4 w;
    w.x = excl;
    w.y = excl + v.x;
    w.z = excl + v.x + v.y;
    w.w = excl + v.x + v.y + v.z;
    ((int4*)(histBT + (size_t)wv * HB))[lane] = w;
    if (lane == 63) totB[wv] = p;
}

// ---------------- exclusive scan of 1280 bucket totals -> bptr ----------------
__global__ __launch_bounds__(256) void k_scanT(const int* __restrict__ totB,
                                               int* __restrict__ bptr) {
    __shared__ int wsum[4];
    int tid = threadIdx.x;
    int loc[5], s = 0;
#pragma unroll
    for (int j = 0; j < 5; ++j) { loc[j] = totB[tid * 5 + j]; s += loc[j]; }
    int lane = tid & 63, w = tid >> 6, v = s;
    for (int d = 1; d < 64; d <<= 1) {
        int t = __shfl_up(v, d);
        if (lane >= d) v += t;
    }
    if (lane == 63) wsum[w] = v;
    __syncthreads();
    if (w == 0 && lane < 4) {
        int t = wsum[lane];
        for (int d = 1; d < 4; d <<= 1) {
            int u = __shfl_up(t, d);
            if (lane >= d) t += u;
        }
        wsum[lane] = t;
    }
    __syncthreads();
    int run = (w > 0 ? wsum[w - 1] : 0) + (v - s);
#pragma unroll
    for (int j = 0; j < 5; ++j) { bptr[tid * 5 + j] = run; run += loc[j]; }
    if (tid == 255) bptr[NB] = run;   // == EE
}

// ---------------- phase 2: scatter into buckets via LDS cursors ----------------
__global__ __launch_bounds__(256) void k_scatterB(const int* __restrict__ ei,
                                                  const float* __restrict__ dinv,
                                                  const int* __restrict__ bptr,
                                                  const int* __restrict__ histBT,
                                                  int2* __restrict__ ep) {
    __shared__ int cur[NB];
    int b = blockIdx.x, tid = threadIdx.x;
    for (int i = tid; i < NB; i += 256) cur[i] = bptr[i] + histBT[(size_t)i * HB + b];
    __syncthreads();
    int e0 = b * ECHUNK;
    for (int e = e0 + tid; e < e0 + ECHUNK; e += 256) {
        int r = ei[e];
        int c = ei[EE + e];
        int bk = (unsigned)c / BNODE;
        int pos = atomicAdd(&cur[bk], 1);
        int2 p;
        p.x = r | ((c - bk * BNODE) << 16);   // src:16b | col_local:6b
        p.y = __float_as_int(dinv[r] * dinv[c]);
        ep[pos] = p;
    }
}

// ---------------- phase 3: in-bucket sort to exact CSC + node ptr emit ----------------
__global__ __launch_bounds__(256) void k_sortB(const int* __restrict__ bptr,
                                               int2* __restrict__ ep,
                                               int* __restrict__ ptr) {
    __shared__ int2 buf[SORTCAP];   // 24 KB
    __shared__ int h40[BNODE];
    __shared__ int pfx[BNODE + 1];
    int b = blockIdx.x, tid = threadIdx.x;
    int e0 = bptr[b], e1 = bptr[b + 1], n = e1 - e0;
    if (tid < BNODE) h40[tid] = 0;
    __syncthreads();
    for (int i = tid; i < n; i += 256) {
        int2 p = ep[e0 + i];
        buf[i] = p;
        atomicAdd(&h40[p.x >> 16], 1);
    }
    __syncthreads();
    if (tid == 0) {
        int run = 0;
#pragma unroll
        for (int j = 0; j < BNODE; ++j) { pfx[j] = run; run += h40[j]; }
        pfx[BNODE] = run;
    }
    __syncthreads();
    if (tid < BNODE) {
        int node = b * BNODE + tid;
        if (node < NN) ptr[node] = e0 + pfx[tid];
        h40[tid] = pfx[tid];     // becomes cursor
    }
    if (tid == 64 && b * BNODE + BNODE >= NN) ptr[NN] = e1;
    __syncthreads();
    for (int i = tid; i < n; i += 256) {
        int2 p = buf[i];
        int cl = p.x >> 16;
        int pos = atomicAdd(&h40[cl], 1);
        int2 q;
        q.x = p.x & 0xFFFF;      // plain src index
        q.y = p.y;
        ep[e0 + pos] = q;
    }
}

// ---------------- W1 -> bf16 hi/lo split ----------------
__global__ void k_w1split(const float* __restrict__ W1, unsigned short* __restrict__ w1h,
                          unsigned short* __restrict__ w1l) {
    int i = blockIdx.x * blockDim.x + threadIdx.x;
    if (i >= HID * IN_DIM) return;
    float v = W1[i];
    unsigned short h = bf16_rne(v);
    unsigned short l = bf16_rne(v - bf16_to_f(h));
    w1h[i] = h;
    w1l[i] = l;
}

// ---------------- GEMM1 via split-bf16 MFMA (round-10 proven config) ----------------
#define BM 64
#define BK 32
__device__ inline int swzA(int row, int b) {
    return row * 64 + (b ^ (int)((((unsigned)row >> 1) & 3u) << 4));
}
__global__ __launch_bounds__(256, 6) void k_gemm1m(const float* __restrict__ x,
                                                   const unsigned short* __restrict__ w1h,
                                                   const unsigned short* __restrict__ w1l,
                                                   const float* __restrict__ b1,
                                                   const float* __restrict__ bnw,
                                                   const float* __restrict__ bnb,
                                                   const float* __restrict__ bnm,
                                                   const float* __restrict__ bnv,
                                                   float* __restrict__ h) {
    __shared__ __align__(16) unsigned short Ah[BM * BK];    // 4 KB
    __shared__ __align__(16) unsigned short Al[BM * BK];    // 4 KB
    __shared__ __align__(16) unsigned short Bh[128 * BK];   // 8 KB
    __shared__ __align__(16) unsigned short Bl[128 * BK];   // 8 KB
    int tid = threadIdx.x;
    int lane = tid & 63;
    int wn = tid >> 6;
    int brow = blockIdx.x * BM;
    int bcol = blockIdx.y * 128;

    int ra = tid >> 2, ck = tid & 3;
    int rb = tid >> 1, cbs = (tid & 1) * 16;

    bool rok = (brow + ra) < NN;
    const float* xa = x + (size_t)(brow + ra) * IN_DIM + ck * 8;
    const unsigned short* bhp = w1h + (size_t)(bcol + rb) * IN_DIM + cbs;
    const unsigned short* blp = w1l + (size_t)(bcol + rb) * IN_DIM + cbs;

    f32x4 acc[4][2];
#pragma unroll
    for (int i = 0; i < 4; ++i)
#pragma unroll
        for (int j = 0; j < 2; ++j) acc[i][j] = (f32x4){0.f, 0.f, 0.f, 0.f};

    int frA = lane & 15;
    int frB = wn * 32 + (lane & 15);
    int fko = (lane >> 4) * 16;

    for (int kt = 0; kt < IN_DIM; kt += BK) {
        float4 v0 = make_float4(0.f, 0.f, 0.f, 0.f), v1 = v0;
        if (rok) { v0 = *(const float4*)(xa + kt); v1 = *(const float4*)(xa + kt + 4); }
        short8 gh0 = *(const short8*)(bhp + kt);
        short8 gh1 = *(const short8*)(bhp + kt + 8);
        short8 gl0 = *(const short8*)(blp + kt);
        short8 gl1 = *(const short8*)(blp + kt + 8);
        union { unsigned short u[8]; short8 v; } uh, ul;
        {
            float vv[8] = {v0.x, v0.y, v0.z, v0.w, v1.x, v1.y, v1.z, v1.w};
#pragma unroll
            for (int j = 0; j < 8; ++j) {
                unsigned short hh = bf16_rne(vv[j]);
                uh.u[j] = hh;
                ul.u[j] = bf16_rne(vv[j] - bf16_to_f(hh));
            }
        }
        __syncthreads();
        {
            int ab = swzA(ra, ck * 16);
            *(short8*)((char*)Ah + ab) = uh.v;
            *(short8*)((char*)Al + ab) = ul.v;
            int bb0 = swzA(rb, cbs * 2);
            int bb1 = swzA(rb, cbs * 2 + 16);
            *(short8*)((char*)Bh + bb0) = gh0;
            *(short8*)((char*)Bh + bb1) = gh1;
            *(short8*)((char*)Bl + bb0) = gl0;
            *(short8*)((char*)Bl + bb1) = gl1;
        }
        __syncthreads();

        short8 afh[4], afl[4];
#pragma unroll
        for (int mi = 0; mi < 4; ++mi) {
            int byte = swzA(frA + mi * 16, fko);
            afh[mi] = *(short8*)((char*)Ah + byte);
            afl[mi] = *(short8*)((char*)Al + byte);
        }
#pragma unroll
        for (int ni = 0; ni < 2; ++ni) {
            int byte = swzA(frB + ni * 16, fko);
            short8 bh = *(short8*)((char*)Bh + byte);
            short8 bl = *(short8*)((char*)Bl + byte);
#pragma unroll
            for (int mi = 0; mi < 4; ++mi) {
                acc[mi][ni] = __builtin_amdgcn_mfma_f32_16x16x32_bf16(afh[mi], bh, acc[mi][ni], 0, 0, 0);
                acc[mi][ni] = __builtin_amdgcn_mfma_f32_16x16x32_bf16(afl[mi], bh, acc[mi][ni], 0, 0, 0);
                acc[mi][ni] = __builtin_amdgcn_mfma_f32_16x16x32_bf16(afh[mi], bl, acc[mi][ni], 0, 0, 0);
            }
        }
    }

    int cbase = bcol + wn * 32 + (lane & 15);
    float scl[2], off[2];
#pragma unroll
    for (int ni = 0; ni < 2; ++ni) {
        int c = cbase + ni * 16;
        float s = bnw[c] * rsqrtf(bnv[c] + BN_EPS);
        scl[ni] = s;
        off[ni] = (b1[c] - bnm[c]) * s + bnb[c];
    }
#pragma unroll
    for (int mi = 0; mi < 4; ++mi) {
        int r0 = brow + mi * 16 + ((lane >> 4) << 2);
#pragma unroll
        for (int ni = 0; ni < 2; ++ni) {
            int c = cbase + ni * 16;
#pragma unroll
            for (int j = 0; j < 4; ++j) {
                int r = r0 + j;
                if (r < NN) {
                    float v = acc[mi][ni][j] * scl[ni] + off[ni];
                    h[(size_t)r * HID + c] = v > 0.f ? v : 0.f;
                }
            }
        }
    }
}

// ---------------- GEMM2: z = h @ W2^T + b2; ping = bf16(z); out = gamma0 * z ----------------
__global__ __launch_bounds__(256) void k_gemm2(const float* __restrict__ h,
                                               const float* __restrict__ W2,
                                               const float* __restrict__ b2,
                                               const float* __restrict__ gamma,
                                               unsigned short* __restrict__ ping,
                                               float* __restrict__ out) {
    __shared__ float W2T[HID * OUT_DIM];
    int tid = threadIdx.x;
    for (int i = tid; i < HID * OUT_DIM; i += 256) {
        int o = i / HID;
        int k = i - o * HID;
        W2T[k * OUT_DIM + o] = W2[i];
    }
    __syncthreads();
    int n = blockIdx.x * 256 + tid;
    if (n >= NN) return;

    float4 acc[10];
#pragma unroll
    for (int o4 = 0; o4 < 10; ++o4) acc[o4] = *(const float4*)&b2[o4 * 4];

    const float4* hr = (const float4*)(h + (size_t)n * HID);
    const float4* wt = (const float4*)W2T;
    for (int j = 0; j < HID / 4; ++j) {
        float4 hv = hr[j];
#pragma unroll
        for (int c = 0; c < 4; ++c) {
            float hk = (c == 0) ? hv.x : (c == 1) ? hv.y : (c == 2) ? hv.z : hv.w;
            const float4* wr = wt + (size_t)(j * 4 + c) * 10;
#pragma unroll
            for (int o4 = 0; o4 < 10; ++o4) {
                float4 w = wr[o4];
                acc[o4].x += hk * w.x;
                acc[o4].y += hk * w.y;
                acc[o4].z += hk * w.z;
                acc[o4].w += hk * w.w;
            }
        }
    }
    float g0 = gamma[0];
    uint2* pp = (uint2*)(ping + (size_t)n * OUT_DIM);
    float4* op = (float4*)(out + (size_t)n * OUT_DIM);
#pragma unroll
    for (int o4 = 0; o4 < 10; ++o4) {
        uint2 w;
        w.x = (unsigned)bf16_rne(acc[o4].x) | ((unsigned)bf16_rne(acc[o4].y) << 16);
        w.y = (unsigned)bf16_rne(acc[o4].z) | ((unsigned)bf16_rne(acc[o4].w) << 16);
        pp[o4] = w;
        float4 g;
        g.x = g0 * acc[o4].x; g.y = g0 * acc[o4].y;
        g.z = g0 * acc[o4].z; g.w = g0 * acc[o4].w;
        op[o4] = g;
    }
}

// ---------------- fused propagation: ALL 10 steps, one cooperative launch ----------------
// Body = round-10's proven spmm5 (48 edges/round, 10 lanes/edge, uint2 gathers,
// bf16 state, 6-slot shfl reduce, fused out RMW), grid-stride over nodes,
// grid.sync() between steps. Minimal registers; PGRID=512 (2 blocks/CU).
__global__ __launch_bounds__(256) void k_prop(const int* __restrict__ ptr,
                                              const int2* __restrict__ ep,
                                              unsigned short* __restrict__ ping,
                                              unsigned short* __restrict__ pong,
                                              const float* __restrict__ gamma,
                                              float* __restrict__ out) {
    cg::grid_group grid = cg::this_grid();
    int gw = blockIdx.x * 4 + (threadIdx.x >> 6);
    int lane = threadIdx.x & 63;
    int es = lane / 10;            // 0..6 (6 => lanes 60-63 idle)
    int fq = lane - es * 10;       // 0..9
    bool act = es < 6;

    const unsigned short* cur = ping;
    unsigned short* nxt = pong;
    for (int k = 1; k <= KSTEPS; ++k) {
        float gk = gamma[k];
        for (int node = gw; node < NN; node += GW) {
            int e0 = ptr[node], e1 = ptr[node + 1];
            float a0 = 0.f, a1 = 0.f, a2 = 0.f, a3 = 0.f;
            for (int base = e0; base < e1; base += 48) {
                int2 pp[8];
#pragma unroll
                for (int g = 0; g < 8; ++g) {
                    int e = base + g * 6 + es;
                    pp[g] = (act && e < e1) ? ep[e] : make_int2(0, 0);
                }
#pragma unroll
                for (int g = 0; g < 8; ++g) {
                    uint2 u = *((const uint2*)(cur + (size_t)pp[g].x * OUT_DIM) + fq);
                    float nm = __int_as_float(pp[g].y);
                    a0 += nm * __uint_as_float(u.x << 16);
                    a1 += nm * __uint_as_float(u.x & 0xFFFF0000u);
                    a2 += nm * __uint_as_float(u.y << 16);
                    a3 += nm * __uint_as_float(u.y & 0xFFFF0000u);
                }
            }
            // reduce across the 6 edge slots: lanes fq, fq+10, ..., fq+50
            float s0 = a0, s1 = a1, s2 = a2, s3 = a3;
#pragma unroll
            for (int j = 1; j < 6; ++j) {
                s0 += __shfl(a0, fq + j * 10);
                s1 += __shfl(a1, fq + j * 10);
                s2 += __shfl(a2, fq + j * 10);
                s3 += __shfl(a3, fq + j * 10);
            }
            if (lane < 10) {
                uint2 w;
                w.x = (unsigned)bf16_rne(s0) | ((unsigned)bf16_rne(s1) << 16);
                w.y = (unsigned)bf16_rne(s2) | ((unsigned)bf16_rne(s3) << 16);
                *((uint2*)(nxt + (size_t)node * OUT_DIM) + lane) = w;
                float4* op = (float4*)(out + (size_t)node * OUT_DIM) + lane;
                float4 ov = *op;
                ov.x += gk * s0; ov.y += gk * s1; ov.z += gk * s2; ov.w += gk * s3;
                *op = ov;
            }
        }
        grid.sync();
        const unsigned short* t = cur;
        cur = nxt;
        nxt = (unsigned short*)t;
    }
}

extern "C" void kernel_launch(void* const* d_in, const int* in_sizes, int n_in,
                              void* d_out, int out_size, void* d_ws, size_t ws_size,
                              hipStream_t stream) {
    const float* x   = (const float*)d_in[0];
    const int*   ei  = (const int*)d_in[1];
    const float* W1  = (const float*)d_in[2];
    const float* b1  = (const float*)d_in[3];
    const float* bnw = (const float*)d_in[4];
    const float* bnb = (const float*)d_in[5];
    const float* bnm = (const float*)d_in[6];
    const float* bnv = (const float*)d_in[7];
    const float* W2  = (const float*)d_in[8];
    const float* b2  = (const float*)d_in[9];
    const float* gamma = (const float*)d_in[10];
    float* out = (float*)d_out;

    char* ws = (char*)d_ws;
    const size_t A = 256;
    auto pad = [&](size_t b) { return (b + A - 1) / A * A; };
    size_t off = 0;
    int*      bptr  = (int*)     (ws + off); off += pad((size_t)(NB + 1) * 4);
    int*      totB  = (int*)     (ws + off); off += pad((size_t)NB * 4);
    float*    dinv  = (float*)   (ws + off); off += pad((size_t)NN * 4);
    int*      ptr   = (int*)     (ws + off); off += pad((size_t)(NN + 1) * 4);
    int2*     ep    = (int2*)    (ws + off); off += pad((size_t)EE * 8);
    float*    h     = (float*)   (ws + off); off += pad((size_t)NN * HID * 4);
    unsigned short* ping = (unsigned short*)(ws + off); off += pad((size_t)NN * OUT_DIM * 2);
    unsigned short* pong = (unsigned short*)(ws + off); off += pad((size_t)NN * OUT_DIM * 2);
    unsigned short* w1h  = (unsigned short*)(ws + off); off += pad((size_t)HID * IN_DIM * 2);
    unsigned short* w1l  = (unsigned short*)(ws + off); off += pad((size_t)HID * IN_DIM * 2);

    // hists alias h (consumed by build before gemm1m writes h)
    unsigned* histR8 = (unsigned*)h;                              // 12.8 MB
    int* histBT = (int*)((char*)h + (size_t)HB * HRW * 4);        // 1.31 MB, [NB][HB]

    // graph build
    k_hist<<<HB, 256, 0, stream>>>(ei, histR8, histBT);
    k_dinv2<<<(NN + 255) / 256, 256, 0, stream>>>(histR8, dinv);
    k_colsumB<<<(NB * 64 + 255) / 256, 256, 0, stream>>>(histBT, totB);
    k_scanT<<<1, 256, 0, stream>>>(totB, bptr);
    k_scatterB<<<HB, 256, 0, stream>>>(ei, dinv, bptr, histBT, ep);
    k_sortB<<<NB, 256, 0, stream>>>(bptr, ep, ptr);

    // MLP
    k_w1split<<<(HID * IN_DIM + 255) / 256, 256, 0, stream>>>(W1, w1h, w1l);
    dim3 g1((NN + BM - 1) / BM, 2);
    k_gemm1m<<<g1, 256, 0, stream>>>(x, w1h, w1l, b1, bnw, bnb, bnm, bnv, h);
    k_gemm2<<<(NN + 255) / 256, 256, 0, stream>>>(h, W2, b2, gamma, ping, out);

    // fused 10-step propagation (cooperative: grid-wide sync between steps)
    {
        void* args[] = {(void*)&ptr, (void*)&ep, (void*)&ping, (void*)&pong,
                        (void*)&gamma, (void*)&out};
        hipLaunchCooperativeKernel((const void*)k_prop, dim3(PGRID), dim3(256),
                                   args, 0, stream);
    }
}

// Round 18
// 430.276 us; speedup vs baseline: 3.4250x; 3.4250x over previous
//
#include <hip/hip_runtime.h>
#include <cstddef>

#define NN 50000
#define EE 1600000
#define IN_DIM 512
#define HID 256
#define OUT_DIM 40
#define KSTEPS 10
#define BN_EPS 1e-5f

#define HB 256                 // histogram/scatter blocks
#define ECHUNK (EE / HB)       // 6250 edges per block
#define BNODE 40               // dest nodes per bucket
#define NB 1280                // buckets (covers 51200 >= NN)
#define HRW ((NN + 3) / 4)     // 12500 words of packed byte counts
#define SORTCAP 3072           // max edges per bucket (mean 1250)

typedef __attribute__((ext_vector_type(8))) short short8;
typedef __attribute__((ext_vector_type(4))) float f32x4;

__device__ inline unsigned short bf16_rne(float v) {
    union { float f; unsigned u; } c; c.f = v;
    unsigned u = c.u;
    unsigned r = u + 0x7fff + ((u >> 16) & 1);
    return (unsigned short)(r >> 16);
}
__device__ inline float bf16_to_f(unsigned short h) {
    union { unsigned u; float f; } c; c.u = ((unsigned)h) << 16;
    return c.f;
}
__device__ inline unsigned short f32_to_f16(float v) {
    union { _Float16 h; unsigned short u; } c; c.h = (_Float16)v; return c.u;
}
__device__ inline float f16_to_f32(unsigned short u) {
    union { unsigned short u; _Float16 h; } c; c.u = u; return (float)c.h;
}

// ---------------- phase 1: LDS histograms; histB stored TRANSPOSED [NB][HB] ----------------
__global__ __launch_bounds__(256) void k_hist(const int* __restrict__ ei,
                                              unsigned* __restrict__ histR8,
                                              int* __restrict__ histBT) {
    __shared__ unsigned hr[HRW];   // 50 KB
    __shared__ int hb[NB];         // 5 KB
    int b = blockIdx.x, tid = threadIdx.x;
    for (int i = tid; i < HRW; i += 256) hr[i] = 0;
    for (int i = tid; i < NB; i += 256) hb[i] = 0;
    __syncthreads();
    int e0 = b * ECHUNK;
    for (int e = e0 + tid; e < e0 + ECHUNK; e += 256) {
        int r = ei[e];
        int c = ei[EE + e];
        atomicAdd(&hr[r >> 2], 1u << ((r & 3) * 8));
        atomicAdd(&hb[(unsigned)c / BNODE], 1);
    }
    __syncthreads();
    unsigned* o = histR8 + (size_t)b * HRW;
    for (int i = tid; i < HRW; i += 256) o[i] = hr[i];
    for (int i = tid; i < NB; i += 256) histBT[(size_t)i * HB + b] = hb[i];
}

// ---------------- row-degree reduce -> dinv ----------------
__global__ void k_dinv2(const unsigned* __restrict__ histR8, float* __restrict__ dinv) {
    int i = blockIdx.x * blockDim.x + threadIdx.x;
    if (i >= NN) return;
    int word = i >> 2, sh = (i & 3) * 8;
    int d = 0;
    for (int blk = 0; blk < HB; ++blk)
        d += (histR8[(size_t)blk * HRW + word] >> sh) & 0xFFu;
    float fd = d < 1 ? 1.0f : (float)d;
    dinv[i] = 1.0f / sqrtf(fd);
}

// ---------------- per-bucket prefix across blocks: one WAVE per bucket ----------------
__global__ __launch_bounds__(256) void k_colsumB(int* __restrict__ histBT,
                                                 int* __restrict__ totB) {
    int wv = (blockIdx.x * 256 + threadIdx.x) >> 6;   // bucket
    int lane = threadIdx.x & 63;
    if (wv >= NB) return;
    int4 v = ((int4*)(histBT + (size_t)wv * HB))[lane];
    int s = v.x + v.y + v.z + v.w;
    int p = s;
    for (int d = 1; d < 64; d <<= 1) {
        int t = __shfl_up(p, d);
        if (lane >= d) p += t;
    }
    int excl = p - s;
    int4 w;
    w.x = excl;
    w.y = excl + v.x;
    w.z = excl + v.x + v.y;
    w.w = excl + v.x + v.y + v.z;
    ((int4*)(histBT + (size_t)wv * HB))[lane] = w;
    if (lane == 63) totB[wv] = p;
}

// ---------------- exclusive scan of 1280 bucket totals -> bptr ----------------
__global__ __launch_bounds__(256) void k_scanT(const int* __restrict__ totB,
                                               int* __restrict__ bptr) {
    __shared__ int wsum[4];
    int tid = threadIdx.x;
    int loc[5], s = 0;
#pragma unroll
    for (int j = 0; j < 5; ++j) { loc[j] = totB[tid * 5 + j]; s += loc[j]; }
    int lane = tid & 63, w = tid >> 6, v = s;
    for (int d = 1; d < 64; d <<= 1) {
        int t = __shfl_up(v, d);
        if (lane >= d) v += t;
    }
    if (lane == 63) wsum[w] = v;
    __syncthreads();
    if (w == 0 && lane < 4) {
        int t = wsum[lane];
        for (int d = 1; d < 4; d <<= 1) {
            int u = __shfl_up(t, d);
            if (lane >= d) t += u;
        }
        wsum[lane] = t;
    }
    __syncthreads();
    int run = (w > 0 ? wsum[w - 1] : 0) + (v - s);
#pragma unroll
    for (int j = 0; j < 5; ++j) { bptr[tid * 5 + j] = run; run += loc[j]; }
    if (tid == 255) bptr[NB] = run;   // == EE
}

// ---------------- phase 2: scatter into buckets via LDS cursors ----------------
__global__ __launch_bounds__(256) void k_scatterB(const int* __restrict__ ei,
                                                  const float* __restrict__ dinv,
                                                  const int* __restrict__ bptr,
                                                  const int* __restrict__ histBT,
                                                  int2* __restrict__ ep) {
    __shared__ int cur[NB];
    int b = blockIdx.x, tid = threadIdx.x;
    for (int i = tid; i < NB; i += 256) cur[i] = bptr[i] + histBT[(size_t)i * HB + b];
    __syncthreads();
    int e0 = b * ECHUNK;
    for (int e = e0 + tid; e < e0 + ECHUNK; e += 256) {
        int r = ei[e];
        int c = ei[EE + e];
        int bk = (unsigned)c / BNODE;
        int pos = atomicAdd(&cur[bk], 1);
        int2 p;
        p.x = r | ((c - bk * BNODE) << 16);   // src:16b | col_local:6b
        p.y = __float_as_int(dinv[r] * dinv[c]);
        ep[pos] = p;
    }
}

// ---------------- phase 3: in-bucket sort -> compressed 4B records + node ptr ----------------
__global__ __launch_bounds__(256) void k_sortB(const int* __restrict__ bptr,
                                               const int2* __restrict__ ep,
                                               unsigned* __restrict__ ep4,
                                               int* __restrict__ ptr) {
    __shared__ int2 buf[SORTCAP];   // 24 KB
    __shared__ int h40[BNODE];
    __shared__ int pfx[BNODE + 1];
    int b = blockIdx.x, tid = threadIdx.x;
    int e0 = bptr[b], e1 = bptr[b + 1], n = e1 - e0;
    if (tid < BNODE) h40[tid] = 0;
    __syncthreads();
    for (int i = tid; i < n; i += 256) {
        int2 p = ep[e0 + i];
        buf[i] = p;
        atomicAdd(&h40[p.x >> 16], 1);
    }
    __syncthreads();
    if (tid == 0) {
        int run = 0;
#pragma unroll
        for (int j = 0; j < BNODE; ++j) { pfx[j] = run; run += h40[j]; }
        pfx[BNODE] = run;
    }
    __syncthreads();
    if (tid < BNODE) {
        int node = b * BNODE + tid;
        if (node < NN) ptr[node] = e0 + pfx[tid];
        h40[tid] = pfx[tid];     // becomes cursor
    }
    if (tid == 64 && b * BNODE + BNODE >= NN) ptr[NN] = e1;
    __syncthreads();
    for (int i = tid; i < n; i += 256) {
        int2 p = buf[i];
        int cl = p.x >> 16;
        int pos = atomicAdd(&h40[cl], 1);
        unsigned short hn = f32_to_f16(__int_as_float(p.y));
        ep4[e0 + pos] = (unsigned)(p.x & 0xFFFF) | ((unsigned)hn << 16);
    }
}

// ---------------- W1 -> bf16 hi/lo split ----------------
__global__ void k_w1split(const float* __restrict__ W1, unsigned short* __restrict__ w1h,
                          unsigned short* __restrict__ w1l) {
    int i = blockIdx.x * blockDim.x + threadIdx.x;
    if (i >= HID * IN_DIM) return;
    float v = W1[i];
    unsigned short h = bf16_rne(v);
    unsigned short l = bf16_rne(v - bf16_to_f(h));
    w1h[i] = h;
    w1l[i] = l;
}

// ---------------- GEMM1 via split-bf16 MFMA (round-10 proven config) ----------------
#define BM 64
#define BK 32
__device__ inline int swzA(int row, int b) {
    return row * 64 + (b ^ (int)((((unsigned)row >> 1) & 3u) << 4));
}
__global__ __launch_bounds__(256, 6) void k_gemm1m(const float* __restrict__ x,
                                                   const unsigned short* __restrict__ w1h,
                                                   const unsigned short* __restrict__ w1l,
                                                   const float* __restrict__ b1,
                                                   const float* __restrict__ bnw,
                                                   const float* __restrict__ bnb,
                                                   const float* __restrict__ bnm,
                                                   const float* __restrict__ bnv,
                                                   float* __restrict__ h) {
    __shared__ __align__(16) unsigned short Ah[BM * BK];    // 4 KB
    __shared__ __align__(16) unsigned short Al[BM * BK];    // 4 KB
    __shared__ __align__(16) unsigned short Bh[128 * BK];   // 8 KB
    __shared__ __align__(16) unsigned short Bl[128 * BK];   // 8 KB
    int tid = threadIdx.x;
    int lane = tid & 63;
    int wn = tid >> 6;
    int brow = blockIdx.x * BM;
    int bcol = blockIdx.y * 128;

    int ra = tid >> 2, ck = tid & 3;
    int rb = tid >> 1, cbs = (tid & 1) * 16;

    bool rok = (brow + ra) < NN;
    const float* xa = x + (size_t)(brow + ra) * IN_DIM + ck * 8;
    const unsigned short* bhp = w1h + (size_t)(bcol + rb) * IN_DIM + cbs;
    const unsigned short* blp = w1l + (size_t)(bcol + rb) * IN_DIM + cbs;

    f32x4 acc[4][2];
#pragma unroll
    for (int i = 0; i < 4; ++i)
#pragma unroll
        for (int j = 0; j < 2; ++j) acc[i][j] = (f32x4){0.f, 0.f, 0.f, 0.f};

    int frA = lane & 15;
    int frB = wn * 32 + (lane & 15);
    int fko = (lane >> 4) * 16;

    for (int kt = 0; kt < IN_DIM; kt += BK) {
        float4 v0 = make_float4(0.f, 0.f, 0.f, 0.f), v1 = v0;
        if (rok) { v0 = *(const float4*)(xa + kt); v1 = *(const float4*)(xa + kt + 4); }
        short8 gh0 = *(const short8*)(bhp + kt);
        short8 gh1 = *(const short8*)(bhp + kt + 8);
        short8 gl0 = *(const short8*)(blp + kt);
        short8 gl1 = *(const short8*)(blp + kt + 8);
        union { unsigned short u[8]; short8 v; } uh, ul;
        {
            float vv[8] = {v0.x, v0.y, v0.z, v0.w, v1.x, v1.y, v1.z, v1.w};
#pragma unroll
            for (int j = 0; j < 8; ++j) {
                unsigned short hh = bf16_rne(vv[j]);
                uh.u[j] = hh;
                ul.u[j] = bf16_rne(vv[j] - bf16_to_f(hh));
            }
        }
        __syncthreads();
        {
            int ab = swzA(ra, ck * 16);
            *(short8*)((char*)Ah + ab) = uh.v;
            *(short8*)((char*)Al + ab) = ul.v;
            int bb0 = swzA(rb, cbs * 2);
            int bb1 = swzA(rb, cbs * 2 + 16);
            *(short8*)((char*)Bh + bb0) = gh0;
            *(short8*)((char*)Bh + bb1) = gh1;
            *(short8*)((char*)Bl + bb0) = gl0;
            *(short8*)((char*)Bl + bb1) = gl1;
        }
        __syncthreads();

        short8 afh[4], afl[4];
#pragma unroll
        for (int mi = 0; mi < 4; ++mi) {
            int byte = swzA(frA + mi * 16, fko);
            afh[mi] = *(short8*)((char*)Ah + byte);
            afl[mi] = *(short8*)((char*)Al + byte);
        }
#pragma unroll
        for (int ni = 0; ni < 2; ++ni) {
            int byte = swzA(frB + ni * 16, fko);
            short8 bh = *(short8*)((char*)Bh + byte);
            short8 bl = *(short8*)((char*)Bl + byte);
#pragma unroll
            for (int mi = 0; mi < 4; ++mi) {
                acc[mi][ni] = __builtin_amdgcn_mfma_f32_16x16x32_bf16(afh[mi], bh, acc[mi][ni], 0, 0, 0);
                acc[mi][ni] = __builtin_amdgcn_mfma_f32_16x16x32_bf16(afl[mi], bh, acc[mi][ni], 0, 0, 0);
                acc[mi][ni] = __builtin_amdgcn_mfma_f32_16x16x32_bf16(afh[mi], bl, acc[mi][ni], 0, 0, 0);
            }
        }
    }

    int cbase = bcol + wn * 32 + (lane & 15);
    float scl[2], off[2];
#pragma unroll
    for (int ni = 0; ni < 2; ++ni) {
        int c = cbase + ni * 16;
        float s = bnw[c] * rsqrtf(bnv[c] + BN_EPS);
        scl[ni] = s;
        off[ni] = (b1[c] - bnm[c]) * s + bnb[c];
    }
#pragma unroll
    for (int mi = 0; mi < 4; ++mi) {
        int r0 = brow + mi * 16 + ((lane >> 4) << 2);
#pragma unroll
        for (int ni = 0; ni < 2; ++ni) {
            int c = cbase + ni * 16;
#pragma unroll
            for (int j = 0; j < 4; ++j) {
                int r = r0 + j;
                if (r < NN) {
                    float v = acc[mi][ni][j] * scl[ni] + off[ni];
                    h[(size_t)r * HID + c] = v > 0.f ? v : 0.f;
                }
            }
        }
    }
}

// ---------------- GEMM2: z = h @ W2^T + b2; ping = bf16(z); out = gamma0 * z ----------------
__global__ __launch_bounds__(256) void k_gemm2(const float* __restrict__ h,
                                               const float* __restrict__ W2,
                                               const float* __restrict__ b2,
                                               const float* __restrict__ gamma,
                                               unsigned short* __restrict__ ping,
                                               float* __restrict__ out) {
    __shared__ float W2T[HID * OUT_DIM];
    int tid = threadIdx.x;
    for (int i = tid; i < HID * OUT_DIM; i += 256) {
        int o = i / HID;
        int k = i - o * HID;
        W2T[k * OUT_DIM + o] = W2[i];
    }
    __syncthreads();
    int n = blockIdx.x * 256 + tid;
    if (n >= NN) return;

    float4 acc[10];
#pragma unroll
    for (int o4 = 0; o4 < 10; ++o4) acc[o4] = *(const float4*)&b2[o4 * 4];

    const float4* hr = (const float4*)(h + (size_t)n * HID);
    const float4* wt = (const float4*)W2T;
    for (int j = 0; j < HID / 4; ++j) {
        float4 hv = hr[j];
#pragma unroll
        for (int c = 0; c < 4; ++c) {
            float hk = (c == 0) ? hv.x : (c == 1) ? hv.y : (c == 2) ? hv.z : hv.w;
            const float4* wr = wt + (size_t)(j * 4 + c) * 10;
#pragma unroll
            for (int o4 = 0; o4 < 10; ++o4) {
                float4 w = wr[o4];
                acc[o4].x += hk * w.x;
                acc[o4].y += hk * w.y;
                acc[o4].z += hk * w.z;
                acc[o4].w += hk * w.w;
            }
        }
    }
    float g0 = gamma[0];
    uint2* pp = (uint2*)(ping + (size_t)n * OUT_DIM);
    float4* op = (float4*)(out + (size_t)n * OUT_DIM);
#pragma unroll
    for (int o4 = 0; o4 < 10; ++o4) {
        uint2 w;
        w.x = (unsigned)bf16_rne(acc[o4].x) | ((unsigned)bf16_rne(acc[o4].y) << 16);
        w.y = (unsigned)bf16_rne(acc[o4].z) | ((unsigned)bf16_rne(acc[o4].w) << 16);
        pp[o4] = w;
        float4 g;
        g.x = g0 * acc[o4].x; g.y = g0 * acc[o4].y;
        g.z = g0 * acc[o4].z; g.w = g0 * acc[o4].w;
        op[o4] = g;
    }
}

// ---------------- propagation step: round-10 spmm5 structure, 4B edge records ----------------
// es = lane/10 (6 edge slots; lanes 60-63 idle), fq = lane%10 (uint2 = 4 bf16
// features). 48 edges/round, 8 direct per-lane edge loads (HW-merged across the
// 10 same-address lanes), unconditional gathers (nm=0 for pads), 6-slot shfl
// reduce, fused fp32 out RMW.
__global__ __launch_bounds__(256) void k_spmm5(const int* __restrict__ ptr,
                                               const unsigned* __restrict__ ep4,
                                               const unsigned short* __restrict__ cur,
                                               unsigned short* __restrict__ nxt,
                                               float* __restrict__ out,
                                               const float* __restrict__ gamma, int k) {
    int wave = (blockIdx.x * blockDim.x + threadIdx.x) >> 6;
    int lane = threadIdx.x & 63;
    if (wave >= NN) return;
    int e0 = ptr[wave], e1 = ptr[wave + 1];
    int es = lane / 10;            // 0..6 (6 => lanes 60-63 idle)
    int fq = lane - es * 10;       // 0..9
    bool act = es < 6;
    float a0 = 0.f, a1 = 0.f, a2 = 0.f, a3 = 0.f;

    for (int base = e0; base < e1; base += 48) {
        unsigned q[8];
#pragma unroll
        for (int g = 0; g < 8; ++g) {
            int e = base + g * 6 + es;
            q[g] = (act && e < e1) ? ep4[e] : 0u;
        }
#pragma unroll
        for (int g = 0; g < 8; ++g) {
            int src = (int)(q[g] & 0xFFFFu);
            float nm = f16_to_f32((unsigned short)(q[g] >> 16));
            uint2 u = *((const uint2*)(cur + (size_t)src * OUT_DIM) + fq);
            a0 += nm * __uint_as_float(u.x << 16);
            a1 += nm * __uint_as_float(u.x & 0xFFFF0000u);
            a2 += nm * __uint_as_float(u.y << 16);
            a3 += nm * __uint_as_float(u.y & 0xFFFF0000u);
        }
    }
    // reduce across the 6 edge slots: lanes fq, fq+10, ..., fq+50
    float s0 = a0, s1 = a1, s2 = a2, s3 = a3;
#pragma unroll
    for (int j = 1; j < 6; ++j) {
        s0 += __shfl(a0, fq + j * 10);
        s1 += __shfl(a1, fq + j * 10);
        s2 += __shfl(a2, fq + j * 10);
        s3 += __shfl(a3, fq + j * 10);
    }
    if (lane < 10) {
        uint2 w;
        w.x = (unsigned)bf16_rne(s0) | ((unsigned)bf16_rne(s1) << 16);
        w.y = (unsigned)bf16_rne(s2) | ((unsigned)bf16_rne(s3) << 16);
        *((uint2*)(nxt + (size_t)wave * OUT_DIM) + lane) = w;
        float gk = gamma[k];
        float4* op = (float4*)(out + (size_t)wave * OUT_DIM) + lane;
        float4 ov = *op;
        ov.x += gk * s0; ov.y += gk * s1; ov.z += gk * s2; ov.w += gk * s3;
        *op = ov;
    }
}

extern "C" void kernel_launch(void* const* d_in, const int* in_sizes, int n_in,
                              void* d_out, int out_size, void* d_ws, size_t ws_size,
                              hipStream_t stream) {
    const float* x   = (const float*)d_in[0];
    const int*   ei  = (const int*)d_in[1];
    const float* W1  = (const float*)d_in[2];
    const float* b1  = (const float*)d_in[3];
    const float* bnw = (const float*)d_in[4];
    const float* bnb = (const float*)d_in[5];
    const float* bnm = (const float*)d_in[6];
    const float* bnv = (const float*)d_in[7];
    const float* W2  = (const float*)d_in[8];
    const float* b2  = (const float*)d_in[9];
    const float* gamma = (const float*)d_in[10];
    float* out = (float*)d_out;

    char* ws = (char*)d_ws;
    const size_t A = 256;
    auto pad = [&](size_t b) { return (b + A - 1) / A * A; };
    size_t off = 0;
    int*      bptr  = (int*)     (ws + off); off += pad((size_t)(NB + 1) * 4);
    int*      totB  = (int*)     (ws + off); off += pad((size_t)NB * 4);
    float*    dinv  = (float*)   (ws + off); off += pad((size_t)NN * 4);
    int*      ptr   = (int*)     (ws + off); off += pad((size_t)(NN + 1) * 4);
    int2*     ep    = (int2*)    (ws + off); off += pad((size_t)EE * 8);   // build-only
    unsigned* ep4   = (unsigned*)(ws + off); off += pad((size_t)EE * 4);
    float*    h     = (float*)   (ws + off); off += pad((size_t)NN * HID * 4);
    unsigned short* ping = (unsigned short*)(ws + off); off += pad((size_t)NN * OUT_DIM * 2);
    unsigned short* pong = (unsigned short*)(ws + off); off += pad((size_t)NN * OUT_DIM * 2);
    unsigned short* w1h  = (unsigned short*)(ws + off); off += pad((size_t)HID * IN_DIM * 2);
    unsigned short* w1l  = (unsigned short*)(ws + off); off += pad((size_t)HID * IN_DIM * 2);

    // hists alias h (consumed by build before gemm1m writes h)
    unsigned* histR8 = (unsigned*)h;                              // 12.8 MB
    int* histBT = (int*)((char*)h + (size_t)HB * HRW * 4);        // 1.31 MB, [NB][HB]

    // graph build
    k_hist<<<HB, 256, 0, stream>>>(ei, histR8, histBT);
    k_dinv2<<<(NN + 255) / 256, 256, 0, stream>>>(histR8, dinv);
    k_colsumB<<<(NB * 64 + 255) / 256, 256, 0, stream>>>(histBT, totB);
    k_scanT<<<1, 256, 0, stream>>>(totB, bptr);
    k_scatterB<<<HB, 256, 0, stream>>>(ei, dinv, bptr, histBT, ep);
    k_sortB<<<NB, 256, 0, stream>>>(bptr, ep, ep4, ptr);

    // MLP
    k_w1split<<<(HID * IN_DIM + 255) / 256, 256, 0, stream>>>(W1, w1h, w1l);
    dim3 g1((NN + BM - 1) / BM, 2);
    k_gemm1m<<<g1, 256, 0, stream>>>(x, w1h, w1l, b1, bnw, bnb, bnm, bnv, h);
    k_gemm2<<<(NN + 255) / 256, 256, 0, stream>>>(h, W2, b2, gamma, ping, out);

    // K propagation steps, ping-pong (bf16 state, fused fp32 out RMW)
    unsigned short* cur = ping;
    unsigned short* nxt = pong;
    for (int k = 1; k <= KSTEPS; ++k) {
        k_spmm5<<<(NN * 64 + 255) / 256, 256, 0, stream>>>(ptr, ep4, cur, nxt, out, gamma, k);
        unsigned short* t = cur; cur = nxt; nxt = t;
    }
}

// Round 19
// 428.667 us; speedup vs baseline: 3.4378x; 1.0038x over previous
//
#include <hip/hip_runtime.h>
#include <cstddef>

#define NN 50000
#define EE 1600000
#define IN_DIM 512
#define HID 256
#define OUT_DIM 40
#define KSTEPS 10
#define BN_EPS 1e-5f

#define HB 256                 // histogram/scatter blocks
#define ECHUNK (EE / HB)       // 6250 edges per block
#define BNODE 40               // dest nodes per bucket
#define NB 1280                // buckets (covers 51200 >= NN)
#define HRW ((NN + 3) / 4)     // 12500 words of packed byte counts
#define SORTCAP 3072           // max edges per bucket (mean 1250)

typedef __attribute__((ext_vector_type(8))) short short8;
typedef __attribute__((ext_vector_type(4))) float f32x4;

__device__ inline unsigned short bf16_rne(float v) {
    union { float f; unsigned u; } c; c.f = v;
    unsigned u = c.u;
    unsigned r = u + 0x7fff + ((u >> 16) & 1);
    return (unsigned short)(r >> 16);
}
__device__ inline float bf16_to_f(unsigned short h) {
    union { unsigned u; float f; } c; c.u = ((unsigned)h) << 16;
    return c.f;
}
__device__ inline unsigned short f32_to_f16(float v) {
    union { _Float16 h; unsigned short u; } c; c.h = (_Float16)v; return c.u;
}
__device__ inline float f16_to_f32(unsigned short u) {
    union { unsigned short u; _Float16 h; } c; c.u = u; return (float)c.h;
}

// ---------------- phase 1: LDS histograms; histB stored TRANSPOSED [NB][HB] ----------------
__global__ __launch_bounds__(256) void k_hist(const int* __restrict__ ei,
                                              unsigned* __restrict__ histR8,
                                              int* __restrict__ histBT) {
    __shared__ unsigned hr[HRW];   // 50 KB
    __shared__ int hb[NB];         // 5 KB
    int b = blockIdx.x, tid = threadIdx.x;
    for (int i = tid; i < HRW; i += 256) hr[i] = 0;
    for (int i = tid; i < NB; i += 256) hb[i] = 0;
    __syncthreads();
    int e0 = b * ECHUNK;
    for (int e = e0 + tid; e < e0 + ECHUNK; e += 256) {
        int r = ei[e];
        int c = ei[EE + e];
        atomicAdd(&hr[r >> 2], 1u << ((r & 3) * 8));
        atomicAdd(&hb[(unsigned)c / BNODE], 1);
    }
    __syncthreads();
    unsigned* o = histR8 + (size_t)b * HRW;
    for (int i = tid; i < HRW; i += 256) o[i] = hr[i];
    for (int i = tid; i < NB; i += 256) histBT[(size_t)i * HB + b] = hb[i];
}

// ---------------- row-degree reduce -> dinv ----------------
__global__ void k_dinv2(const unsigned* __restrict__ histR8, float* __restrict__ dinv) {
    int i = blockIdx.x * blockDim.x + threadIdx.x;
    if (i >= NN) return;
    int word = i >> 2, sh = (i & 3) * 8;
    int d = 0;
    for (int blk = 0; blk < HB; ++blk)
        d += (histR8[(size_t)blk * HRW + word] >> sh) & 0xFFu;
    float fd = d < 1 ? 1.0f : (float)d;
    dinv[i] = 1.0f / sqrtf(fd);
}

// ---------------- per-bucket prefix across blocks: one WAVE per bucket ----------------
__global__ __launch_bounds__(256) void k_colsumB(int* __restrict__ histBT,
                                                 int* __restrict__ totB) {
    int wv = (blockIdx.x * 256 + threadIdx.x) >> 6;   // bucket
    int lane = threadIdx.x & 63;
    if (wv >= NB) return;
    int4 v = ((int4*)(histBT + (size_t)wv * HB))[lane];
    int s = v.x + v.y + v.z + v.w;
    int p = s;
    for (int d = 1; d < 64; d <<= 1) {
        int t = __shfl_up(p, d);
        if (lane >= d) p += t;
    }
    int excl = p - s;
    int4 w;
    w.x = excl;
    w.y = excl + v.x;
    w.z = excl + v.x + v.y;
    w.w = excl + v.x + v.y + v.z;
    ((int4*)(histBT + (size_t)wv * HB))[lane] = w;
    if (lane == 63) totB[wv] = p;
}

// ---------------- exclusive scan of 1280 bucket totals -> bptr ----------------
__global__ __launch_bounds__(256) void k_scanT(const int* __restrict__ totB,
                                               int* __restrict__ bptr) {
    __shared__ int wsum[4];
    int tid = threadIdx.x;
    int loc[5], s = 0;
#pragma unroll
    for (int j = 0; j < 5; ++j) { loc[j] = totB[tid * 5 + j]; s += loc[j]; }
    int lane = tid & 63, w = tid >> 6, v = s;
    for (int d = 1; d < 64; d <<= 1) {
        int t = __shfl_up(v, d);
        if (lane >= d) v += t;
    }
    if (lane == 63) wsum[w] = v;
    __syncthreads();
    if (w == 0 && lane < 4) {
        int t = wsum[lane];
        for (int d = 1; d < 4; d <<= 1) {
            int u = __shfl_up(t, d);
            if (lane >= d) t += u;
        }
        wsum[lane] = t;
    }
    __syncthreads();
    int run = (w > 0 ? wsum[w - 1] : 0) + (v - s);
#pragma unroll
    for (int j = 0; j < 5; ++j) { bptr[tid * 5 + j] = run; run += loc[j]; }
    if (tid == 255) bptr[NB] = run;   // == EE
}

// ---------------- phase 2: scatter into buckets via LDS cursors ----------------
__global__ __launch_bounds__(256) void k_scatterB(const int* __restrict__ ei,
                                                  const float* __restrict__ dinv,
                                                  const int* __restrict__ bptr,
                                                  const int* __restrict__ histBT,
                                                  int2* __restrict__ ep) {
    __shared__ int cur[NB];
    int b = blockIdx.x, tid = threadIdx.x;
    for (int i = tid; i < NB; i += 256) cur[i] = bptr[i] + histBT[(size_t)i * HB + b];
    __syncthreads();
    int e0 = b * ECHUNK;
    for (int e = e0 + tid; e < e0 + ECHUNK; e += 256) {
        int r = ei[e];
        int c = ei[EE + e];
        int bk = (unsigned)c / BNODE;
        int pos = atomicAdd(&cur[bk], 1);
        int2 p;
        p.x = r | ((c - bk * BNODE) << 16);   // src:16b | col_local:6b
        p.y = __float_as_int(dinv[r] * dinv[c]);
        ep[pos] = p;
    }
}

// ---------------- phase 3: in-bucket sort -> compressed 4B records + node ptr ----------------
__global__ __launch_bounds__(256) void k_sortB(const int* __restrict__ bptr,
                                               const int2* __restrict__ ep,
                                               unsigned* __restrict__ ep4,
                                               int* __restrict__ ptr) {
    __shared__ int2 buf[SORTCAP];   // 24 KB
    __shared__ int h40[BNODE];
    __shared__ int pfx[BNODE + 1];
    int b = blockIdx.x, tid = threadIdx.x;
    int e0 = bptr[b], e1 = bptr[b + 1], n = e1 - e0;
    if (tid < BNODE) h40[tid] = 0;
    __syncthreads();
    for (int i = tid; i < n; i += 256) {
        int2 p = ep[e0 + i];
        buf[i] = p;
        atomicAdd(&h40[p.x >> 16], 1);
    }
    __syncthreads();
    if (tid == 0) {
        int run = 0;
#pragma unroll
        for (int j = 0; j < BNODE; ++j) { pfx[j] = run; run += h40[j]; }
        pfx[BNODE] = run;
    }
    __syncthreads();
    if (tid < BNODE) {
        int node = b * BNODE + tid;
        if (node < NN) ptr[node] = e0 + pfx[tid];
        h40[tid] = pfx[tid];     // becomes cursor
    }
    if (tid == 64 && b * BNODE + BNODE >= NN) ptr[NN] = e1;
    __syncthreads();
    for (int i = tid; i < n; i += 256) {
        int2 p = buf[i];
        int cl = p.x >> 16;
        int pos = atomicAdd(&h40[cl], 1);
        unsigned short hn = f32_to_f16(__int_as_float(p.y));
        ep4[e0 + pos] = (unsigned)(p.x & 0xFFFF) | ((unsigned)hn << 16);
    }
}

// ---------------- W1 -> bf16 hi/lo split ----------------
__global__ void k_w1split(const float* __restrict__ W1, unsigned short* __restrict__ w1h,
                          unsigned short* __restrict__ w1l) {
    int i = blockIdx.x * blockDim.x + threadIdx.x;
    if (i >= HID * IN_DIM) return;
    float v = W1[i];
    unsigned short h = bf16_rne(v);
    unsigned short l = bf16_rne(v - bf16_to_f(h));
    w1h[i] = h;
    w1l[i] = l;
}

// ---------------- GEMM1: split-bf16 MFMA, double-buffered LDS, ONE barrier/iter ----------------
// BM=64, BN split in halves of 128 (grid 782x2), BK=32. 4 waves, wave tile 64x32
// (acc 4x2). 48 KB LDS (2 buffers) -> 3 blocks/CU. Loads for tile kt+1 issue at
// the top of iter kt and drain under its MFMAs; write to the other buffer; one
// barrier publishes tile kt+1 AND retires all reads of buf[kt&1].
#define BM 64
#define BK 32
__device__ inline int swzA(int row, int b) {
    return row * 64 + (b ^ (int)((((unsigned)row >> 1) & 3u) << 4));
}
__global__ __launch_bounds__(256, 3) void k_gemm1m(const float* __restrict__ x,
                                                   const unsigned short* __restrict__ w1h,
                                                   const unsigned short* __restrict__ w1l,
                                                   const float* __restrict__ b1,
                                                   const float* __restrict__ bnw,
                                                   const float* __restrict__ bnb,
                                                   const float* __restrict__ bnm,
                                                   const float* __restrict__ bnv,
                                                   float* __restrict__ h) {
    __shared__ __align__(16) unsigned short Ah[2][BM * BK];    // 2 x 4 KB
    __shared__ __align__(16) unsigned short Al[2][BM * BK];    // 2 x 4 KB
    __shared__ __align__(16) unsigned short Bh[2][128 * BK];   // 2 x 8 KB
    __shared__ __align__(16) unsigned short Bl[2][128 * BK];   // 2 x 8 KB
    int tid = threadIdx.x;
    int lane = tid & 63;
    int wn = tid >> 6;
    int brow = blockIdx.x * BM;
    int bcol = blockIdx.y * 128;

    int ra = tid >> 2, ck = tid & 3;
    int rb = tid >> 1, cbs = (tid & 1) * 16;

    bool rok = (brow + ra) < NN;
    const float* xa = x + (size_t)(brow + ra) * IN_DIM + ck * 8;
    const unsigned short* bhp = w1h + (size_t)(bcol + rb) * IN_DIM + cbs;
    const unsigned short* blp = w1l + (size_t)(bcol + rb) * IN_DIM + cbs;

    f32x4 acc[4][2];
#pragma unroll
    for (int i = 0; i < 4; ++i)
#pragma unroll
        for (int j = 0; j < 2; ++j) acc[i][j] = (f32x4){0.f, 0.f, 0.f, 0.f};

    int frA = lane & 15;
    int frB = wn * 32 + (lane & 15);
    int fko = (lane >> 4) * 16;

    int abyte = swzA(ra, ck * 16);
    int bbyte0 = swzA(rb, cbs * 2);
    int bbyte1 = swzA(rb, cbs * 2 + 16);

    // tile-0 loads + convert + write buf0
    float4 v0 = make_float4(0.f, 0.f, 0.f, 0.f), v1 = v0;
    if (rok) { v0 = *(const float4*)(xa); v1 = *(const float4*)(xa + 4); }
    short8 gh0 = *(const short8*)(bhp);
    short8 gh1 = *(const short8*)(bhp + 8);
    short8 gl0 = *(const short8*)(blp);
    short8 gl1 = *(const short8*)(blp + 8);
    {
        union { unsigned short u[8]; short8 v; } uh, ul;
        float vv[8] = {v0.x, v0.y, v0.z, v0.w, v1.x, v1.y, v1.z, v1.w};
#pragma unroll
        for (int j = 0; j < 8; ++j) {
            unsigned short hh = bf16_rne(vv[j]);
            uh.u[j] = hh;
            ul.u[j] = bf16_rne(vv[j] - bf16_to_f(hh));
        }
        *(short8*)((char*)Ah[0] + abyte) = uh.v;
        *(short8*)((char*)Al[0] + abyte) = ul.v;
        *(short8*)((char*)Bh[0] + bbyte0) = gh0;
        *(short8*)((char*)Bh[0] + bbyte1) = gh1;
        *(short8*)((char*)Bl[0] + bbyte0) = gl0;
        *(short8*)((char*)Bl[0] + bbyte1) = gl1;
    }
    __syncthreads();

    const int NIT = IN_DIM / BK;   // 16
    for (int it = 0; it < NIT; ++it) {
        int cb = it & 1;
        int nb = cb ^ 1;
        bool more = (it + 1) < NIT;
        if (more) {   // issue next-tile loads; they drain under this tile's MFMAs
            int kn = (it + 1) * BK;
            v0 = make_float4(0.f, 0.f, 0.f, 0.f); v1 = v0;
            if (rok) { v0 = *(const float4*)(xa + kn); v1 = *(const float4*)(xa + kn + 4); }
            gh0 = *(const short8*)(bhp + kn);
            gh1 = *(const short8*)(bhp + kn + 8);
            gl0 = *(const short8*)(blp + kn);
            gl1 = *(const short8*)(blp + kn + 8);
        }

        // compute tile it from buf[cb]
        short8 afh[4], afl[4];
#pragma unroll
        for (int mi = 0; mi < 4; ++mi) {
            int byte = swzA(frA + mi * 16, fko);
            afh[mi] = *(short8*)((char*)Ah[cb] + byte);
            afl[mi] = *(short8*)((char*)Al[cb] + byte);
        }
#pragma unroll
        for (int ni = 0; ni < 2; ++ni) {
            int byte = swzA(frB + ni * 16, fko);
            short8 bh = *(short8*)((char*)Bh[cb] + byte);
            short8 bl = *(short8*)((char*)Bl[cb] + byte);
#pragma unroll
            for (int mi = 0; mi < 4; ++mi) {
                acc[mi][ni] = __builtin_amdgcn_mfma_f32_16x16x32_bf16(afh[mi], bh, acc[mi][ni], 0, 0, 0);
                acc[mi][ni] = __builtin_amdgcn_mfma_f32_16x16x32_bf16(afl[mi], bh, acc[mi][ni], 0, 0, 0);
                acc[mi][ni] = __builtin_amdgcn_mfma_f32_16x16x32_bf16(afh[mi], bl, acc[mi][ni], 0, 0, 0);
            }
        }

        if (more) {   // convert + write tile it+1 into the other buffer
            union { unsigned short u[8]; short8 v; } uh, ul;
            float vv[8] = {v0.x, v0.y, v0.z, v0.w, v1.x, v1.y, v1.z, v1.w};
#pragma unroll
            for (int j = 0; j < 8; ++j) {
                unsigned short hh = bf16_rne(vv[j]);
                uh.u[j] = hh;
                ul.u[j] = bf16_rne(vv[j] - bf16_to_f(hh));
            }
            *(short8*)((char*)Ah[nb] + abyte) = uh.v;
            *(short8*)((char*)Al[nb] + abyte) = ul.v;
            *(short8*)((char*)Bh[nb] + bbyte0) = gh0;
            *(short8*)((char*)Bh[nb] + bbyte1) = gh1;
            *(short8*)((char*)Bl[nb] + bbyte0) = gl0;
            *(short8*)((char*)Bl[nb] + bbyte1) = gl1;
        }
        __syncthreads();   // publish tile it+1; retire reads of buf[cb]
    }

    int cbase = bcol + wn * 32 + (lane & 15);
    float scl[2], off[2];
#pragma unroll
    for (int ni = 0; ni < 2; ++ni) {
        int c = cbase + ni * 16;
        float s = bnw[c] * rsqrtf(bnv[c] + BN_EPS);
        scl[ni] = s;
        off[ni] = (b1[c] - bnm[c]) * s + bnb[c];
    }
#pragma unroll
    for (int mi = 0; mi < 4; ++mi) {
        int r0 = brow + mi * 16 + ((lane >> 4) << 2);
#pragma unroll
        for (int ni = 0; ni < 2; ++ni) {
            int c = cbase + ni * 16;
#pragma unroll
            for (int j = 0; j < 4; ++j) {
                int r = r0 + j;
                if (r < NN) {
                    float v = acc[mi][ni][j] * scl[ni] + off[ni];
                    h[(size_t)r * HID + c] = v > 0.f ? v : 0.f;
                }
            }
        }
    }
}

// ---------------- GEMM2: z = h @ W2^T + b2; ping = bf16(z); out = gamma0 * z ----------------
__global__ __launch_bounds__(256) void k_gemm2(const float* __restrict__ h,
                                               const float* __restrict__ W2,
                                               const float* __restrict__ b2,
                                               const float* __restrict__ gamma,
                                               unsigned short* __restrict__ ping,
                                               float* __restrict__ out) {
    __shared__ float W2T[HID * OUT_DIM];
    int tid = threadIdx.x;
    for (int i = tid; i < HID * OUT_DIM; i += 256) {
        int o = i / HID;
        int k = i - o * HID;
        W2T[k * OUT_DIM + o] = W2[i];
    }
    __syncthreads();
    int n = blockIdx.x * 256 + tid;
    if (n >= NN) return;

    float4 acc[10];
#pragma unroll
    for (int o4 = 0; o4 < 10; ++o4) acc[o4] = *(const float4*)&b2[o4 * 4];

    const float4* hr = (const float4*)(h + (size_t)n * HID);
    const float4* wt = (const float4*)W2T;
    for (int j = 0; j < HID / 4; ++j) {
        float4 hv = hr[j];
#pragma unroll
        for (int c = 0; c < 4; ++c) {
            float hk = (c == 0) ? hv.x : (c == 1) ? hv.y : (c == 2) ? hv.z : hv.w;
            const float4* wr = wt + (size_t)(j * 4 + c) * 10;
#pragma unroll
            for (int o4 = 0; o4 < 10; ++o4) {
                float4 w = wr[o4];
                acc[o4].x += hk * w.x;
                acc[o4].y += hk * w.y;
                acc[o4].z += hk * w.z;
                acc[o4].w += hk * w.w;
            }
        }
    }
    float g0 = gamma[0];
    uint2* pp = (uint2*)(ping + (size_t)n * OUT_DIM);
    float4* op = (float4*)(out + (size_t)n * OUT_DIM);
#pragma unroll
    for (int o4 = 0; o4 < 10; ++o4) {
        uint2 w;
        w.x = (unsigned)bf16_rne(acc[o4].x) | ((unsigned)bf16_rne(acc[o4].y) << 16);
        w.y = (unsigned)bf16_rne(acc[o4].z) | ((unsigned)bf16_rne(acc[o4].w) << 16);
        pp[o4] = w;
        float4 g;
        g.x = g0 * acc[o4].x; g.y = g0 * acc[o4].y;
        g.z = g0 * acc[o4].z; g.w = g0 * acc[o4].w;
        op[o4] = g;
    }
}

// ---------------- propagation step: round-10 spmm5 structure, 4B edge records ----------------
__global__ __launch_bounds__(256) void k_spmm5(const int* __restrict__ ptr,
                                               const unsigned* __restrict__ ep4,
                                               const unsigned short* __restrict__ cur,
                                               unsigned short* __restrict__ nxt,
                                               float* __restrict__ out,
                                               const float* __restrict__ gamma, int k) {
    int wave = (blockIdx.x * blockDim.x + threadIdx.x) >> 6;
    int lane = threadIdx.x & 63;
    if (wave >= NN) return;
    int e0 = ptr[wave], e1 = ptr[wave + 1];
    int es = lane / 10;            // 0..6 (6 => lanes 60-63 idle)
    int fq = lane - es * 10;       // 0..9
    bool act = es < 6;
    float a0 = 0.f, a1 = 0.f, a2 = 0.f, a3 = 0.f;

    for (int base = e0; base < e1; base += 48) {
        unsigned q[8];
#pragma unroll
        for (int g = 0; g < 8; ++g) {
            int e = base + g * 6 + es;
            q[g] = (act && e < e1) ? ep4[e] : 0u;
        }
#pragma unroll
        for (int g = 0; g < 8; ++g) {
            int src = (int)(q[g] & 0xFFFFu);
            float nm = f16_to_f32((unsigned short)(q[g] >> 16));
            uint2 u = *((const uint2*)(cur + (size_t)src * OUT_DIM) + fq);
            a0 += nm * __uint_as_float(u.x << 16);
            a1 += nm * __uint_as_float(u.x & 0xFFFF0000u);
            a2 += nm * __uint_as_float(u.y << 16);
            a3 += nm * __uint_as_float(u.y & 0xFFFF0000u);
        }
    }
    float s0 = a0, s1 = a1, s2 = a2, s3 = a3;
#pragma unroll
    for (int j = 1; j < 6; ++j) {
        s0 += __shfl(a0, fq + j * 10);
        s1 += __shfl(a1, fq + j * 10);
        s2 += __shfl(a2, fq + j * 10);
        s3 += __shfl(a3, fq + j * 10);
    }
    if (lane < 10) {
        uint2 w;
        w.x = (unsigned)bf16_rne(s0) | ((unsigned)bf16_rne(s1) << 16);
        w.y = (unsigned)bf16_rne(s2) | ((unsigned)bf16_rne(s3) << 16);
        *((uint2*)(nxt + (size_t)wave * OUT_DIM) + lane) = w;
        float gk = gamma[k];
        float4* op = (float4*)(out + (size_t)wave * OUT_DIM) + lane;
        float4 ov = *op;
        ov.x += gk * s0; ov.y += gk * s1; ov.z += gk * s2; ov.w += gk * s3;
        *op = ov;
    }
}

extern "C" void kernel_launch(void* const* d_in, const int* in_sizes, int n_in,
                              void* d_out, int out_size, void* d_ws, size_t ws_size,
                              hipStream_t stream) {
    const float* x   = (const float*)d_in[0];
    const int*   ei  = (const int*)d_in[1];
    const float* W1  = (const float*)d_in[2];
    const float* b1  = (const float*)d_in[3];
    const float* bnw = (const float*)d_in[4];
    const float* bnb = (const float*)d_in[5];
    const float* bnm = (const float*)d_in[6];
    const float* bnv = (const float*)d_in[7];
    const float* W2  = (const float*)d_in[8];
    const float* b2  = (const float*)d_in[9];
    const float* gamma = (const float*)d_in[10];
    float* out = (float*)d_out;

    char* ws = (char*)d_ws;
    const size_t A = 256;
    auto pad = [&](size_t b) { return (b + A - 1) / A * A; };
    size_t off = 0;
    int*      bptr  = (int*)     (ws + off); off += pad((size_t)(NB + 1) * 4);
    int*      totB  = (int*)     (ws + off); off += pad((size_t)NB * 4);
    float*    dinv  = (float*)   (ws + off); off += pad((size_t)NN * 4);
    int*      ptr   = (int*)     (ws + off); off += pad((size_t)(NN + 1) * 4);
    int2*     ep    = (int2*)    (ws + off); off += pad((size_t)EE * 8);   // build-only
    unsigned* ep4   = (unsigned*)(ws + off); off += pad((size_t)EE * 4);
    float*    h     = (float*)   (ws + off); off += pad((size_t)NN * HID * 4);
    unsigned short* ping = (unsigned short*)(ws + off); off += pad((size_t)NN * OUT_DIM * 2);
    unsigned short* pong = (unsigned short*)(ws + off); off += pad((size_t)NN * OUT_DIM * 2);
    unsigned short* w1h  = (unsigned short*)(ws + off); off += pad((size_t)HID * IN_DIM * 2);
    unsigned short* w1l  = (unsigned short*)(ws + off); off += pad((size_t)HID * IN_DIM * 2);

    // hists alias h (consumed by build before gemm1m writes h)
    unsigned* histR8 = (unsigned*)h;                              // 12.8 MB
    int* histBT = (int*)((char*)h + (size_t)HB * HRW * 4);        // 1.31 MB, [NB][HB]

    // graph build
    k_hist<<<HB, 256, 0, stream>>>(ei, histR8, histBT);
    k_dinv2<<<(NN + 255) / 256, 256, 0, stream>>>(histR8, dinv);
    k_colsumB<<<(NB * 64 + 255) / 256, 256, 0, stream>>>(histBT, totB);
    k_scanT<<<1, 256, 0, stream>>>(totB, bptr);
    k_scatterB<<<HB, 256, 0, stream>>>(ei, dinv, bptr, histBT, ep);
    k_sortB<<<NB, 256, 0, stream>>>(bptr, ep, ep4, ptr);

    // MLP
    k_w1split<<<(HID * IN_DIM + 255) / 256, 256, 0, stream>>>(W1, w1h, w1l);
    dim3 g1((NN + BM - 1) / BM, 2);
    k_gemm1m<<<g1, 256, 0, stream>>>(x, w1h, w1l, b1, bnw, bnb, bnm, bnv, h);
    k_gemm2<<<(NN + 255) / 256, 256, 0, stream>>>(h, W2, b2, gamma, ping, out);

    // K propagation steps, ping-pong (bf16 state, fused fp32 out RMW)
    unsigned short* cur = ping;
    unsigned short* nxt = pong;
    for (int k = 1; k <= KSTEPS; ++k) {
        k_spmm5<<<(NN * 64 + 255) / 256, 256, 0, stream>>>(ptr, ep4, cur, nxt, out, gamma, k);
        unsigned short* t = cur; cur = nxt; nxt = t;
    }
}

// Round 20
// 406.584 us; speedup vs baseline: 3.6246x; 1.0543x over previous
//
#include <hip/hip_runtime.h>
#include <cstddef>

#define NN 50000
#define EE 1600000
#define IN_DIM 512
#define HID 256
#define OUT_DIM 40
#define KSTEPS 10
#define BN_EPS 1e-5f

#define HB 256                 // histogram/scatter blocks
#define ECHUNK (EE / HB)       // 6250 edges per block
#define BNODE 40               // dest nodes per bucket
#define NB 1280                // buckets (covers 51200 >= NN)
#define HRW ((NN + 3) / 4)     // 12500 words of packed byte counts
#define SORTCAP 3072           // max edges per bucket (mean 1250)

typedef __attribute__((ext_vector_type(8))) short short8;
typedef __attribute__((ext_vector_type(4))) float f32x4;

__device__ inline unsigned short bf16_rne(float v) {
    union { float f; unsigned u; } c; c.f = v;
    unsigned u = c.u;
    unsigned r = u + 0x7fff + ((u >> 16) & 1);
    return (unsigned short)(r >> 16);
}
__device__ inline float bf16_to_f(unsigned short h) {
    union { unsigned u; float f; } c; c.u = ((unsigned)h) << 16;
    return c.f;
}
__device__ inline unsigned short f32_to_f16(float v) {
    union { _Float16 h; unsigned short u; } c; c.h = (_Float16)v; return c.u;
}
__device__ inline float f16_to_f32(unsigned short u) {
    union { unsigned short u; _Float16 h; } c; c.u = u; return (float)c.h;
}

// ---------------- phase 1: LDS histograms; histB stored TRANSPOSED [NB][HB] ----------------
__global__ __launch_bounds__(256) void k_hist(const int* __restrict__ ei,
                                              unsigned* __restrict__ histR8,
                                              int* __restrict__ histBT) {
    __shared__ unsigned hr[HRW];   // 50 KB
    __shared__ int hb[NB];         // 5 KB
    int b = blockIdx.x, tid = threadIdx.x;
    for (int i = tid; i < HRW; i += 256) hr[i] = 0;
    for (int i = tid; i < NB; i += 256) hb[i] = 0;
    __syncthreads();
    int e0 = b * ECHUNK;
    for (int e = e0 + tid; e < e0 + ECHUNK; e += 256) {
        int r = ei[e];
        int c = ei[EE + e];
        atomicAdd(&hr[r >> 2], 1u << ((r & 3) * 8));
        atomicAdd(&hb[(unsigned)c / BNODE], 1);
    }
    __syncthreads();
    unsigned* o = histR8 + (size_t)b * HRW;
    for (int i = tid; i < HRW; i += 256) o[i] = hr[i];
    for (int i = tid; i < NB; i += 256) histBT[(size_t)i * HB + b] = hb[i];
}

// ---------------- row-degree reduce -> dinv ----------------
__global__ void k_dinv2(const unsigned* __restrict__ histR8, float* __restrict__ dinv) {
    int i = blockIdx.x * blockDim.x + threadIdx.x;
    if (i >= NN) return;
    int word = i >> 2, sh = (i & 3) * 8;
    int d = 0;
    for (int blk = 0; blk < HB; ++blk)
        d += (histR8[(size_t)blk * HRW + word] >> sh) & 0xFFu;
    float fd = d < 1 ? 1.0f : (float)d;
    dinv[i] = 1.0f / sqrtf(fd);
}

// ---------------- per-bucket prefix across blocks: one WAVE per bucket ----------------
__global__ __launch_bounds__(256) void k_colsumB(int* __restrict__ histBT,
                                                 int* __restrict__ totB) {
    int wv = (blockIdx.x * 256 + threadIdx.x) >> 6;   // bucket
    int lane = threadIdx.x & 63;
    if (wv >= NB) return;
    int4 v = ((int4*)(histBT + (size_t)wv * HB))[lane];
    int s = v.x + v.y + v.z + v.w;
    int p = s;
    for (int d = 1; d < 64; d <<= 1) {
        int t = __shfl_up(p, d);
        if (lane >= d) p += t;
    }
    int excl = p - s;
    int4 w;
    w.x = excl;
    w.y = excl + v.x;
    w.z = excl + v.x + v.y;
    w.w = excl + v.x + v.y + v.z;
    ((int4*)(histBT + (size_t)wv * HB))[lane] = w;
    if (lane == 63) totB[wv] = p;
}

// ---------------- exclusive scan of 1280 bucket totals -> bptr ----------------
__global__ __launch_bounds__(256) void k_scanT(const int* __restrict__ totB,
                                               int* __restrict__ bptr) {
    __shared__ int wsum[4];
    int tid = threadIdx.x;
    int loc[5], s = 0;
#pragma unroll
    for (int j = 0; j < 5; ++j) { loc[j] = totB[tid * 5 + j]; s += loc[j]; }
    int lane = tid & 63, w = tid >> 6, v = s;
    for (int d = 1; d < 64; d <<= 1) {
        int t = __shfl_up(v, d);
        if (lane >= d) v += t;
    }
    if (lane == 63) wsum[w] = v;
    __syncthreads();
    if (w == 0 && lane < 4) {
        int t = wsum[lane];
        for (int d = 1; d < 4; d <<= 1) {
            int u = __shfl_up(t, d);
            if (lane >= d) t += u;
        }
        wsum[lane] = t;
    }
    __syncthreads();
    int run = (w > 0 ? wsum[w - 1] : 0) + (v - s);
#pragma unroll
    for (int j = 0; j < 5; ++j) { bptr[tid * 5 + j] = run; run += loc[j]; }
    if (tid == 255) bptr[NB] = run;   // == EE
}

// ---------------- phase 2: scatter into buckets via LDS cursors ----------------
__global__ __launch_bounds__(256) void k_scatterB(const int* __restrict__ ei,
                                                  const float* __restrict__ dinv,
                                                  const int* __restrict__ bptr,
                                                  const int* __restrict__ histBT,
                                                  int2* __restrict__ ep) {
    __shared__ int cur[NB];
    int b = blockIdx.x, tid = threadIdx.x;
    for (int i = tid; i < NB; i += 256) cur[i] = bptr[i] + histBT[(size_t)i * HB + b];
    __syncthreads();
    int e0 = b * ECHUNK;
    for (int e = e0 + tid; e < e0 + ECHUNK; e += 256) {
        int r = ei[e];
        int c = ei[EE + e];
        int bk = (unsigned)c / BNODE;
        int pos = atomicAdd(&cur[bk], 1);
        int2 p;
        p.x = r | ((c - bk * BNODE) << 16);   // src:16b | col_local:6b
        p.y = __float_as_int(dinv[r] * dinv[c]);
        ep[pos] = p;
    }
}

// ---------------- phase 3: in-bucket sort -> compressed 4B records + node ptr ----------------
__global__ __launch_bounds__(256) void k_sortB(const int* __restrict__ bptr,
                                               const int2* __restrict__ ep,
                                               unsigned* __restrict__ ep4,
                                               int* __restrict__ ptr) {
    __shared__ int2 buf[SORTCAP];   // 24 KB
    __shared__ int h40[BNODE];
    __shared__ int pfx[BNODE + 1];
    int b = blockIdx.x, tid = threadIdx.x;
    int e0 = bptr[b], e1 = bptr[b + 1], n = e1 - e0;
    if (tid < BNODE) h40[tid] = 0;
    __syncthreads();
    for (int i = tid; i < n; i += 256) {
        int2 p = ep[e0 + i];
        buf[i] = p;
        atomicAdd(&h40[p.x >> 16], 1);
    }
    __syncthreads();
    if (tid == 0) {
        int run = 0;
#pragma unroll
        for (int j = 0; j < BNODE; ++j) { pfx[j] = run; run += h40[j]; }
        pfx[BNODE] = run;
    }
    __syncthreads();
    if (tid < BNODE) {
        int node = b * BNODE + tid;
        if (node < NN) ptr[node] = e0 + pfx[tid];
        h40[tid] = pfx[tid];     // becomes cursor
    }
    if (tid == 64 && b * BNODE + BNODE >= NN) ptr[NN] = e1;
    __syncthreads();
    for (int i = tid; i < n; i += 256) {
        int2 p = buf[i];
        int cl = p.x >> 16;
        int pos = atomicAdd(&h40[cl], 1);
        unsigned short hn = f32_to_f16(__int_as_float(p.y));
        ep4[e0 + pos] = (unsigned)(p.x & 0xFFFF) | ((unsigned)hn << 16);
    }
}

// ---------------- W1 -> bf16 hi/lo split ----------------
__global__ void k_w1split(const float* __restrict__ W1, unsigned short* __restrict__ w1h,
                          unsigned short* __restrict__ w1l) {
    int i = blockIdx.x * blockDim.x + threadIdx.x;
    if (i >= HID * IN_DIM) return;
    float v = W1[i];
    unsigned short h = bf16_rne(v);
    unsigned short l = bf16_rne(v - bf16_to_f(h));
    w1h[i] = h;
    w1l[i] = l;
}

// ---------------- GEMM1 via split-bf16 MFMA (round-10/18 proven config) ----------------
#define BM 64
#define BK 32
__device__ inline int swzA(int row, int b) {
    return row * 64 + (b ^ (int)((((unsigned)row >> 1) & 3u) << 4));
}
__global__ __launch_bounds__(256, 6) void k_gemm1m(const float* __restrict__ x,
                                                   const unsigned short* __restrict__ w1h,
                                                   const unsigned short* __restrict__ w1l,
                                                   const float* __restrict__ b1,
                                                   const float* __restrict__ bnw,
                                                   const float* __restrict__ bnb,
                                                   const float* __restrict__ bnm,
                                                   const float* __restrict__ bnv,
                                                   float* __restrict__ h) {
    __shared__ __align__(16) unsigned short Ah[BM * BK];    // 4 KB
    __shared__ __align__(16) unsigned short Al[BM * BK];    // 4 KB
    __shared__ __align__(16) unsigned short Bh[128 * BK];   // 8 KB
    __shared__ __align__(16) unsigned short Bl[128 * BK];   // 8 KB
    int tid = threadIdx.x;
    int lane = tid & 63;
    int wn = tid >> 6;
    int brow = blockIdx.x * BM;
    int bcol = blockIdx.y * 128;

    int ra = tid >> 2, ck = tid & 3;
    int rb = tid >> 1, cbs = (tid & 1) * 16;

    bool rok = (brow + ra) < NN;
    const float* xa = x + (size_t)(brow + ra) * IN_DIM + ck * 8;
    const unsigned short* bhp = w1h + (size_t)(bcol + rb) * IN_DIM + cbs;
    const unsigned short* blp = w1l + (size_t)(bcol + rb) * IN_DIM + cbs;

    f32x4 acc[4][2];
#pragma unroll
    for (int i = 0; i < 4; ++i)
#pragma unroll
        for (int j = 0; j < 2; ++j) acc[i][j] = (f32x4){0.f, 0.f, 0.f, 0.f};

    int frA = lane & 15;
    int frB = wn * 32 + (lane & 15);
    int fko = (lane >> 4) * 16;

    for (int kt = 0; kt < IN_DIM; kt += BK) {
        float4 v0 = make_float4(0.f, 0.f, 0.f, 0.f), v1 = v0;
        if (rok) { v0 = *(const float4*)(xa + kt); v1 = *(const float4*)(xa + kt + 4); }
        short8 gh0 = *(const short8*)(bhp + kt);
        short8 gh1 = *(const short8*)(bhp + kt + 8);
        short8 gl0 = *(const short8*)(blp + kt);
        short8 gl1 = *(const short8*)(blp + kt + 8);
        union { unsigned short u[8]; short8 v; } uh, ul;
        {
            float vv[8] = {v0.x, v0.y, v0.z, v0.w, v1.x, v1.y, v1.z, v1.w};
#pragma unroll
            for (int j = 0; j < 8; ++j) {
                unsigned short hh = bf16_rne(vv[j]);
                uh.u[j] = hh;
                ul.u[j] = bf16_rne(vv[j] - bf16_to_f(hh));
            }
        }
        __syncthreads();
        {
            int ab = swzA(ra, ck * 16);
            *(short8*)((char*)Ah + ab) = uh.v;
            *(short8*)((char*)Al + ab) = ul.v;
            int bb0 = swzA(rb, cbs * 2);
            int bb1 = swzA(rb, cbs * 2 + 16);
            *(short8*)((char*)Bh + bb0) = gh0;
            *(short8*)((char*)Bh + bb1) = gh1;
            *(short8*)((char*)Bl + bb0) = gl0;
            *(short8*)((char*)Bl + bb1) = gl1;
        }
        __syncthreads();

        short8 afh[4], afl[4];
#pragma unroll
        for (int mi = 0; mi < 4; ++mi) {
            int byte = swzA(frA + mi * 16, fko);
            afh[mi] = *(short8*)((char*)Ah + byte);
            afl[mi] = *(short8*)((char*)Al + byte);
        }
#pragma unroll
        for (int ni = 0; ni < 2; ++ni) {
            int byte = swzA(frB + ni * 16, fko);
            short8 bh = *(short8*)((char*)Bh + byte);
            short8 bl = *(short8*)((char*)Bl + byte);
#pragma unroll
            for (int mi = 0; mi < 4; ++mi) {
                acc[mi][ni] = __builtin_amdgcn_mfma_f32_16x16x32_bf16(afh[mi], bh, acc[mi][ni], 0, 0, 0);
                acc[mi][ni] = __builtin_amdgcn_mfma_f32_16x16x32_bf16(afl[mi], bh, acc[mi][ni], 0, 0, 0);
                acc[mi][ni] = __builtin_amdgcn_mfma_f32_16x16x32_bf16(afh[mi], bl, acc[mi][ni], 0, 0, 0);
            }
        }
    }

    int cbase = bcol + wn * 32 + (lane & 15);
    float scl[2], off[2];
#pragma unroll
    for (int ni = 0; ni < 2; ++ni) {
        int c = cbase + ni * 16;
        float s = bnw[c] * rsqrtf(bnv[c] + BN_EPS);
        scl[ni] = s;
        off[ni] = (b1[c] - bnm[c]) * s + bnb[c];
    }
#pragma unroll
    for (int mi = 0; mi < 4; ++mi) {
        int r0 = brow + mi * 16 + ((lane >> 4) << 2);
#pragma unroll
        for (int ni = 0; ni < 2; ++ni) {
            int c = cbase + ni * 16;
#pragma unroll
            for (int j = 0; j < 4; ++j) {
                int r = r0 + j;
                if (r < NN) {
                    float v = acc[mi][ni][j] * scl[ni] + off[ni];
                    h[(size_t)r * HID + c] = v > 0.f ? v : 0.f;
                }
            }
        }
    }
}

// ---------------- GEMM2: z = h @ W2^T + b2; hbuf0 = bf16(z) ----------------
__global__ __launch_bounds__(256) void k_gemm2(const float* __restrict__ h,
                                               const float* __restrict__ W2,
                                               const float* __restrict__ b2,
                                               unsigned short* __restrict__ hbuf0) {
    __shared__ float W2T[HID * OUT_DIM];
    int tid = threadIdx.x;
    for (int i = tid; i < HID * OUT_DIM; i += 256) {
        int o = i / HID;
        int k = i - o * HID;
        W2T[k * OUT_DIM + o] = W2[i];
    }
    __syncthreads();
    int n = blockIdx.x * 256 + tid;
    if (n >= NN) return;

    float4 acc[10];
#pragma unroll
    for (int o4 = 0; o4 < 10; ++o4) acc[o4] = *(const float4*)&b2[o4 * 4];

    const float4* hr = (const float4*)(h + (size_t)n * HID);
    const float4* wt = (const float4*)W2T;
    for (int j = 0; j < HID / 4; ++j) {
        float4 hv = hr[j];
#pragma unroll
        for (int c = 0; c < 4; ++c) {
            float hk = (c == 0) ? hv.x : (c == 1) ? hv.y : (c == 2) ? hv.z : hv.w;
            const float4* wr = wt + (size_t)(j * 4 + c) * 10;
#pragma unroll
            for (int o4 = 0; o4 < 10; ++o4) {
                float4 w = wr[o4];
                acc[o4].x += hk * w.x;
                acc[o4].y += hk * w.y;
                acc[o4].z += hk * w.z;
                acc[o4].w += hk * w.w;
            }
        }
    }
    uint2* pp = (uint2*)(hbuf0 + (size_t)n * OUT_DIM);
#pragma unroll
    for (int o4 = 0; o4 < 10; ++o4) {
        uint2 w;
        w.x = (unsigned)bf16_rne(acc[o4].x) | ((unsigned)bf16_rne(acc[o4].y) << 16);
        w.y = (unsigned)bf16_rne(acc[o4].z) | ((unsigned)bf16_rne(acc[o4].w) << 16);
        pp[o4] = w;
    }
}

// ---------------- propagation step: spmm5 structure, NO out RMW (deferred) ----------------
// es = lane/10 (6 edge slots; lanes 60-63 idle), fq = lane%10 (uint2 = 4 bf16
// features). 48 edges/round, 8 direct per-lane edge loads, unconditional
// gathers (nm=0 for pads), 6-slot shfl reduce; writes bf16 h_k only.
__global__ __launch_bounds__(256) void k_spmm5(const int* __restrict__ ptr,
                                               const unsigned* __restrict__ ep4,
                                               const unsigned short* __restrict__ cur,
                                               unsigned short* __restrict__ nxt) {
    int wave = (blockIdx.x * blockDim.x + threadIdx.x) >> 6;
    int lane = threadIdx.x & 63;
    if (wave >= NN) return;
    int e0 = ptr[wave], e1 = ptr[wave + 1];
    int es = lane / 10;            // 0..6 (6 => lanes 60-63 idle)
    int fq = lane - es * 10;       // 0..9
    bool act = es < 6;
    float a0 = 0.f, a1 = 0.f, a2 = 0.f, a3 = 0.f;

    for (int base = e0; base < e1; base += 48) {
        unsigned q[8];
#pragma unroll
        for (int g = 0; g < 8; ++g) {
            int e = base + g * 6 + es;
            q[g] = (act && e < e1) ? ep4[e] : 0u;
        }
#pragma unroll
        for (int g = 0; g < 8; ++g) {
            int src = (int)(q[g] & 0xFFFFu);
            float nm = f16_to_f32((unsigned short)(q[g] >> 16));
            uint2 u = *((const uint2*)(cur + (size_t)src * OUT_DIM) + fq);
            a0 += nm * __uint_as_float(u.x << 16);
            a1 += nm * __uint_as_float(u.x & 0xFFFF0000u);
            a2 += nm * __uint_as_float(u.y << 16);
            a3 += nm * __uint_as_float(u.y & 0xFFFF0000u);
        }
    }
    float s0 = a0, s1 = a1, s2 = a2, s3 = a3;
#pragma unroll
    for (int j = 1; j < 6; ++j) {
        s0 += __shfl(a0, fq + j * 10);
        s1 += __shfl(a1, fq + j * 10);
        s2 += __shfl(a2, fq + j * 10);
        s3 += __shfl(a3, fq + j * 10);
    }
    if (lane < 10) {
        uint2 w;
        w.x = (unsigned)bf16_rne(s0) | ((unsigned)bf16_rne(s1) << 16);
        w.y = (unsigned)bf16_rne(s2) | ((unsigned)bf16_rne(s3) << 16);
        *((uint2*)(nxt + (size_t)wave * OUT_DIM) + lane) = w;
    }
}

// ---------------- final: out = sum_k gamma[k] * h_k ----------------
__global__ __launch_bounds__(256) void k_final(const unsigned short* __restrict__ hbuf0,
                                               const unsigned short* __restrict__ hchain,
                                               const float* __restrict__ gamma,
                                               float* __restrict__ out) {
    int idx = blockIdx.x * 256 + threadIdx.x;      // one uint2 (4 features)
    if (idx >= NN * 10) return;
    float g[KSTEPS + 1];
#pragma unroll
    for (int k = 0; k <= KSTEPS; ++k) g[k] = gamma[k];

    uint2 v = *((const uint2*)hbuf0 + idx);
    float a0 = g[0] * __uint_as_float(v.x << 16);
    float a1 = g[0] * __uint_as_float(v.x & 0xFFFF0000u);
    float a2 = g[0] * __uint_as_float(v.y << 16);
    float a3 = g[0] * __uint_as_float(v.y & 0xFFFF0000u);
#pragma unroll
    for (int k = 1; k <= KSTEPS; ++k) {
        uint2 u = *((const uint2*)(hchain + (size_t)(k - 1) * NN * OUT_DIM) + idx);
        a0 += g[k] * __uint_as_float(u.x << 16);
        a1 += g[k] * __uint_as_float(u.x & 0xFFFF0000u);
        a2 += g[k] * __uint_as_float(u.y << 16);
        a3 += g[k] * __uint_as_float(u.y & 0xFFFF0000u);
    }
    ((float4*)out)[idx] = make_float4(a0, a1, a2, a3);
}

extern "C" void kernel_launch(void* const* d_in, const int* in_sizes, int n_in,
                              void* d_out, int out_size, void* d_ws, size_t ws_size,
                              hipStream_t stream) {
    const float* x   = (const float*)d_in[0];
    const int*   ei  = (const int*)d_in[1];
    const float* W1  = (const float*)d_in[2];
    const float* b1  = (const float*)d_in[3];
    const float* bnw = (const float*)d_in[4];
    const float* bnb = (const float*)d_in[5];
    const float* bnm = (const float*)d_in[6];
    const float* bnv = (const float*)d_in[7];
    const float* W2  = (const float*)d_in[8];
    const float* b2  = (const float*)d_in[9];
    const float* gamma = (const float*)d_in[10];
    float* out = (float*)d_out;

    char* ws = (char*)d_ws;
    const size_t A = 256;
    auto pad = [&](size_t b) { return (b + A - 1) / A * A; };
    size_t off = 0;
    int*      bptr  = (int*)     (ws + off); off += pad((size_t)(NB + 1) * 4);
    int*      totB  = (int*)     (ws + off); off += pad((size_t)NB * 4);
    float*    dinv  = (float*)   (ws + off); off += pad((size_t)NN * 4);
    int*      ptr   = (int*)     (ws + off); off += pad((size_t)(NN + 1) * 4);
    int2*     ep    = (int2*)    (ws + off); off += pad((size_t)EE * 8);   // build-only
    unsigned* ep4   = (unsigned*)(ws + off); off += pad((size_t)EE * 4);
    float*    h     = (float*)   (ws + off); off += pad((size_t)NN * HID * 4);
    unsigned short* hbuf0 = (unsigned short*)(ws + off); off += pad((size_t)NN * OUT_DIM * 2);
    unsigned short* w1h   = (unsigned short*)(ws + off); off += pad((size_t)HID * IN_DIM * 2);
    unsigned short* w1l   = (unsigned short*)(ws + off); off += pad((size_t)HID * IN_DIM * 2);

    // aliases into h:
    //  - hists: consumed by build BEFORE gemm1m writes h
    //  - hchain[0..9] (10 x 4 MB = 40 MB <= 51.2 MB): written by spmm AFTER
    //    gemm2 consumed h; read by k_final
    unsigned* histR8 = (unsigned*)h;                              // 12.8 MB
    int* histBT = (int*)((char*)h + (size_t)HB * HRW * 4);        // 1.31 MB, [NB][HB]
    unsigned short* hchain = (unsigned short*)h;                  // 10 x NN*OUT_DIM bf16

    // graph build
    k_hist<<<HB, 256, 0, stream>>>(ei, histR8, histBT);
    k_dinv2<<<(NN + 255) / 256, 256, 0, stream>>>(histR8, dinv);
    k_colsumB<<<(NB * 64 + 255) / 256, 256, 0, stream>>>(histBT, totB);
    k_scanT<<<1, 256, 0, stream>>>(totB, bptr);
    k_scatterB<<<HB, 256, 0, stream>>>(ei, dinv, bptr, histBT, ep);
    k_sortB<<<NB, 256, 0, stream>>>(bptr, ep, ep4, ptr);

    // MLP
    k_w1split<<<(HID * IN_DIM + 255) / 256, 256, 0, stream>>>(W1, w1h, w1l);
    dim3 g1((NN + BM - 1) / BM, 2);
    k_gemm1m<<<g1, 256, 0, stream>>>(x, w1h, w1l, b1, bnw, bnb, bnm, bnv, h);
    k_gemm2<<<(NN + 255) / 256, 256, 0, stream>>>(h, W2, b2, hbuf0);

    // K propagation steps; h_k chain lives in (dead) h
    for (int k = 1; k <= KSTEPS; ++k) {
        const unsigned short* cur = (k == 1) ? hbuf0
                                             : hchain + (size_t)(k - 2) * NN * OUT_DIM;
        unsigned short* nxt = hchain + (size_t)(k - 1) * NN * OUT_DIM;
        k_spmm5<<<(NN * 64 + 255) / 256, 256, 0, stream>>>(ptr, ep4, cur, nxt);
    }

    // out = sum_k gamma[k] * h_k
    k_final<<<(NN * 10 + 255) / 256, 256, 0, stream>>>(hbuf0, hchain, gamma, out);
}

// Round 21
// 404.663 us; speedup vs baseline: 3.6418x; 1.0047x over previous
//
#include <hip/hip_runtime.h>
#include <cstddef>

#define NN 50000
#define EE 1600000
#define IN_DIM 512
#define HID 256
#define OUT_DIM 40
#define KSTEPS 10
#define BN_EPS 1e-5f

#define HB 256                 // histogram/scatter blocks
#define ECHUNK (EE / HB)       // 6250 edges per block
#define BNODE 40               // dest nodes per bucket
#define NB 1280                // buckets (covers 51200 >= NN)
#define HRW ((NN + 3) / 4)     // 12500 words of packed byte counts
#define SORTCAP 3072           // max edges per bucket (mean 1250)

// k_aux block-range split
#define DINV_B ((NN + 255) / 256)             // 196
#define COL_B  ((NB * 64 + 255) / 256)        // 320
#define W1_B   ((HID * IN_DIM + 255) / 256)   // 512

typedef __attribute__((ext_vector_type(8))) short short8;
typedef __attribute__((ext_vector_type(4))) float f32x4;

__device__ inline unsigned short bf16_rne(float v) {
    union { float f; unsigned u; } c; c.f = v;
    unsigned u = c.u;
    unsigned r = u + 0x7fff + ((u >> 16) & 1);
    return (unsigned short)(r >> 16);
}
__device__ inline float bf16_to_f(unsigned short h) {
    union { unsigned u; float f; } c; c.u = ((unsigned)h) << 16;
    return c.f;
}
__device__ inline unsigned short f32_to_f16(float v) {
    union { _Float16 h; unsigned short u; } c; c.h = (_Float16)v; return c.u;
}
__device__ inline float f16_to_f32(unsigned short u) {
    union { unsigned short u; _Float16 h; } c; c.u = u; return (float)c.h;
}

// ---------------- phase 1: LDS histograms; histB stored TRANSPOSED [NB][HB] ----------------
__global__ __launch_bounds__(256) void k_hist(const int* __restrict__ ei,
                                              unsigned* __restrict__ histR8,
                                              int* __restrict__ histBT) {
    __shared__ unsigned hr[HRW];   // 50 KB
    __shared__ int hb[NB];         // 5 KB
    int b = blockIdx.x, tid = threadIdx.x;
    for (int i = tid; i < HRW; i += 256) hr[i] = 0;
    for (int i = tid; i < NB; i += 256) hb[i] = 0;
    __syncthreads();
    int e0 = b * ECHUNK;
    for (int e = e0 + tid; e < e0 + ECHUNK; e += 256) {
        int r = ei[e];
        int c = ei[EE + e];
        atomicAdd(&hr[r >> 2], 1u << ((r & 3) * 8));
        atomicAdd(&hb[(unsigned)c / BNODE], 1);
    }
    __syncthreads();
    unsigned* o = histR8 + (size_t)b * HRW;
    for (int i = tid; i < HRW; i += 256) o[i] = hr[i];
    for (int i = tid; i < NB; i += 256) histBT[(size_t)i * HB + b] = hb[i];
}

// ---------------- fused aux: dinv2 | colsumB | w1split (block-range split, no LDS) ----------------
__global__ __launch_bounds__(256) void k_aux(const unsigned* __restrict__ histR8,
                                             float* __restrict__ dinv,
                                             int* __restrict__ histBT,
                                             int* __restrict__ totB,
                                             const float* __restrict__ W1,
                                             unsigned short* __restrict__ w1h,
                                             unsigned short* __restrict__ w1l) {
    int blk = blockIdx.x;
    if (blk < DINV_B) {
        // ---- row-degree reduce -> dinv ----
        int i = blk * 256 + threadIdx.x;
        if (i >= NN) return;
        int word = i >> 2, sh = (i & 3) * 8;
        int d = 0;
        for (int b = 0; b < HB; ++b)
            d += (histR8[(size_t)b * HRW + word] >> sh) & 0xFFu;
        float fd = d < 1 ? 1.0f : (float)d;
        dinv[i] = 1.0f / sqrtf(fd);
    } else if (blk < DINV_B + COL_B) {
        // ---- per-bucket prefix across blocks: one wave per bucket ----
        int t = (blk - DINV_B) * 256 + threadIdx.x;
        int wv = t >> 6;
        int lane = threadIdx.x & 63;
        if (wv >= NB) return;
        int4 v = ((int4*)(histBT + (size_t)wv * HB))[lane];
        int s = v.x + v.y + v.z + v.w;
        int p = s;
        for (int d = 1; d < 64; d <<= 1) {
            int u = __shfl_up(p, d);
            if (lane >= d) p += u;
        }
        int excl = p - s;
        int4 w;
        w.x = excl;
        w.y = excl + v.x;
        w.z = excl + v.x + v.y;
        w.w = excl + v.x + v.y + v.z;
        ((int4*)(histBT + (size_t)wv * HB))[lane] = w;
        if (lane == 63) totB[wv] = p;
    } else {
        // ---- W1 -> bf16 hi/lo split ----
        int i = (blk - DINV_B - COL_B) * 256 + threadIdx.x;
        if (i >= HID * IN_DIM) return;
        float v = W1[i];
        unsigned short h = bf16_rne(v);
        unsigned short l = bf16_rne(v - bf16_to_f(h));
        w1h[i] = h;
        w1l[i] = l;
    }
}

// ---------------- exclusive scan of 1280 bucket totals -> bptr ----------------
__global__ __launch_bounds__(256) void k_scanT(const int* __restrict__ totB,
                                               int* __restrict__ bptr) {
    __shared__ int wsum[4];
    int tid = threadIdx.x;
    int loc[5], s = 0;
#pragma unroll
    for (int j = 0; j < 5; ++j) { loc[j] = totB[tid * 5 + j]; s += loc[j]; }
    int lane = tid & 63, w = tid >> 6, v = s;
    for (int d = 1; d < 64; d <<= 1) {
        int t = __shfl_up(v, d);
        if (lane >= d) v += t;
    }
    if (lane == 63) wsum[w] = v;
    __syncthreads();
    if (w == 0 && lane < 4) {
        int t = wsum[lane];
        for (int d = 1; d < 4; d <<= 1) {
            int u = __shfl_up(t, d);
            if (lane >= d) t += u;
        }
        wsum[lane] = t;
    }
    __syncthreads();
    int run = (w > 0 ? wsum[w - 1] : 0) + (v - s);
#pragma unroll
    for (int j = 0; j < 5; ++j) { bptr[tid * 5 + j] = run; run += loc[j]; }
    if (tid == 255) bptr[NB] = run;   // == EE
}

// ---------------- phase 2: scatter into buckets via LDS cursors ----------------
__global__ __launch_bounds__(256) void k_scatterB(const int* __restrict__ ei,
                                                  const float* __restrict__ dinv,
                                                  const int* __restrict__ bptr,
                                                  const int* __restrict__ histBT,
                                                  int2* __restrict__ ep) {
    __shared__ int cur[NB];
    int b = blockIdx.x, tid = threadIdx.x;
    for (int i = tid; i < NB; i += 256) cur[i] = bptr[i] + histBT[(size_t)i * HB + b];
    __syncthreads();
    int e0 = b * ECHUNK;
    for (int e = e0 + tid; e < e0 + ECHUNK; e += 256) {
        int r = ei[e];
        int c = ei[EE + e];
        int bk = (unsigned)c / BNODE;
        int pos = atomicAdd(&cur[bk], 1);
        int2 p;
        p.x = r | ((c - bk * BNODE) << 16);   // src:16b | col_local:6b
        p.y = __float_as_int(dinv[r] * dinv[c]);
        ep[pos] = p;
    }
}

// ---------------- phase 3: in-bucket sort -> compressed 4B records + node ptr ----------------
__global__ __launch_bounds__(256) void k_sortB(const int* __restrict__ bptr,
                                               const int2* __restrict__ ep,
                                               unsigned* __restrict__ ep4,
                                               int* __restrict__ ptr) {
    __shared__ int2 buf[SORTCAP];   // 24 KB
    __shared__ int h40[BNODE];
    __shared__ int pfx[BNODE + 1];
    int b = blockIdx.x, tid = threadIdx.x;
    int e0 = bptr[b], e1 = bptr[b + 1], n = e1 - e0;
    if (tid < BNODE) h40[tid] = 0;
    __syncthreads();
    for (int i = tid; i < n; i += 256) {
        int2 p = ep[e0 + i];
        buf[i] = p;
        atomicAdd(&h40[p.x >> 16], 1);
    }
    __syncthreads();
    if (tid == 0) {
        int run = 0;
#pragma unroll
        for (int j = 0; j < BNODE; ++j) { pfx[j] = run; run += h40[j]; }
        pfx[BNODE] = run;
    }
    __syncthreads();
    if (tid < BNODE) {
        int node = b * BNODE + tid;
        if (node < NN) ptr[node] = e0 + pfx[tid];
        h40[tid] = pfx[tid];     // becomes cursor
    }
    if (tid == 64 && b * BNODE + BNODE >= NN) ptr[NN] = e1;
    __syncthreads();
    for (int i = tid; i < n; i += 256) {
        int2 p = buf[i];
        int cl = p.x >> 16;
        int pos = atomicAdd(&h40[cl], 1);
        unsigned short hn = f32_to_f16(__int_as_float(p.y));
        ep4[e0 + pos] = (unsigned)(p.x & 0xFFFF) | ((unsigned)hn << 16);
    }
}

// ---------------- GEMM1 via split-bf16 MFMA (round-10/18 proven config) ----------------
#define BM 64
#define BK 32
__device__ inline int swzA(int row, int b) {
    return row * 64 + (b ^ (int)((((unsigned)row >> 1) & 3u) << 4));
}
__global__ __launch_bounds__(256, 6) void k_gemm1m(const float* __restrict__ x,
                                                   const unsigned short* __restrict__ w1h,
                                                   const unsigned short* __restrict__ w1l,
                                                   const float* __restrict__ b1,
                                                   const float* __restrict__ bnw,
                                                   const float* __restrict__ bnb,
                                                   const float* __restrict__ bnm,
                                                   const float* __restrict__ bnv,
                                                   float* __restrict__ h) {
    __shared__ __align__(16) unsigned short Ah[BM * BK];    // 4 KB
    __shared__ __align__(16) unsigned short Al[BM * BK];    // 4 KB
    __shared__ __align__(16) unsigned short Bh[128 * BK];   // 8 KB
    __shared__ __align__(16) unsigned short Bl[128 * BK];   // 8 KB
    int tid = threadIdx.x;
    int lane = tid & 63;
    int wn = tid >> 6;
    int brow = blockIdx.x * BM;
    int bcol = blockIdx.y * 128;

    int ra = tid >> 2, ck = tid & 3;
    int rb = tid >> 1, cbs = (tid & 1) * 16;

    bool rok = (brow + ra) < NN;
    const float* xa = x + (size_t)(brow + ra) * IN_DIM + ck * 8;
    const unsigned short* bhp = w1h + (size_t)(bcol + rb) * IN_DIM + cbs;
    const unsigned short* blp = w1l + (size_t)(bcol + rb) * IN_DIM + cbs;

    f32x4 acc[4][2];
#pragma unroll
    for (int i = 0; i < 4; ++i)
#pragma unroll
        for (int j = 0; j < 2; ++j) acc[i][j] = (f32x4){0.f, 0.f, 0.f, 0.f};

    int frA = lane & 15;
    int frB = wn * 32 + (lane & 15);
    int fko = (lane >> 4) * 16;

    for (int kt = 0; kt < IN_DIM; kt += BK) {
        float4 v0 = make_float4(0.f, 0.f, 0.f, 0.f), v1 = v0;
        if (rok) { v0 = *(const float4*)(xa + kt); v1 = *(const float4*)(xa + kt + 4); }
        short8 gh0 = *(const short8*)(bhp + kt);
        short8 gh1 = *(const short8*)(bhp + kt + 8);
        short8 gl0 = *(const short8*)(blp + kt);
        short8 gl1 = *(const short8*)(blp + kt + 8);
        union { unsigned short u[8]; short8 v; } uh, ul;
        {
            float vv[8] = {v0.x, v0.y, v0.z, v0.w, v1.x, v1.y, v1.z, v1.w};
#pragma unroll
            for (int j = 0; j < 8; ++j) {
                unsigned short hh = bf16_rne(vv[j]);
                uh.u[j] = hh;
                ul.u[j] = bf16_rne(vv[j] - bf16_to_f(hh));
            }
        }
        __syncthreads();
        {
            int ab = swzA(ra, ck * 16);
            *(short8*)((char*)Ah + ab) = uh.v;
            *(short8*)((char*)Al + ab) = ul.v;
            int bb0 = swzA(rb, cbs * 2);
            int bb1 = swzA(rb, cbs * 2 + 16);
            *(short8*)((char*)Bh + bb0) = gh0;
            *(short8*)((char*)Bh + bb1) = gh1;
            *(short8*)((char*)Bl + bb0) = gl0;
            *(short8*)((char*)Bl + bb1) = gl1;
        }
        __syncthreads();

        short8 afh[4], afl[4];
#pragma unroll
        for (int mi = 0; mi < 4; ++mi) {
            int byte = swzA(frA + mi * 16, fko);
            afh[mi] = *(short8*)((char*)Ah + byte);
            afl[mi] = *(short8*)((char*)Al + byte);
        }
#pragma unroll
        for (int ni = 0; ni < 2; ++ni) {
            int byte = swzA(frB + ni * 16, fko);
            short8 bh = *(short8*)((char*)Bh + byte);
            short8 bl = *(short8*)((char*)Bl + byte);
#pragma unroll
            for (int mi = 0; mi < 4; ++mi) {
                acc[mi][ni] = __builtin_amdgcn_mfma_f32_16x16x32_bf16(afh[mi], bh, acc[mi][ni], 0, 0, 0);
                acc[mi][ni] = __builtin_amdgcn_mfma_f32_16x16x32_bf16(afl[mi], bh, acc[mi][ni], 0, 0, 0);
                acc[mi][ni] = __builtin_amdgcn_mfma_f32_16x16x32_bf16(afh[mi], bl, acc[mi][ni], 0, 0, 0);
            }
        }
    }

    int cbase = bcol + wn * 32 + (lane & 15);
    float scl[2], off[2];
#pragma unroll
    for (int ni = 0; ni < 2; ++ni) {
        int c = cbase + ni * 16;
        float s = bnw[c] * rsqrtf(bnv[c] + BN_EPS);
        scl[ni] = s;
        off[ni] = (b1[c] - bnm[c]) * s + bnb[c];
    }
#pragma unroll
    for (int mi = 0; mi < 4; ++mi) {
        int r0 = brow + mi * 16 + ((lane >> 4) << 2);
#pragma unroll
        for (int ni = 0; ni < 2; ++ni) {
            int c = cbase + ni * 16;
#pragma unroll
            for (int j = 0; j < 4; ++j) {
                int r = r0 + j;
                if (r < NN) {
                    float v = acc[mi][ni][j] * scl[ni] + off[ni];
                    h[(size_t)r * HID + c] = v > 0.f ? v : 0.f;
                }
            }
        }
    }
}

// ---------------- GEMM2: z = h @ W2^T + b2; hbuf0 = bf16(z) ----------------
__global__ __launch_bounds__(256) void k_gemm2(const float* __restrict__ h,
                                               const float* __restrict__ W2,
                                               const float* __restrict__ b2,
                                               unsigned short* __restrict__ hbuf0) {
    __shared__ float W2T[HID * OUT_DIM];
    int tid = threadIdx.x;
    for (int i = tid; i < HID * OUT_DIM; i += 256) {
        int o = i / HID;
        int k = i - o * HID;
        W2T[k * OUT_DIM + o] = W2[i];
    }
    __syncthreads();
    int n = blockIdx.x * 256 + tid;
    if (n >= NN) return;

    float4 acc[10];
#pragma unroll
    for (int o4 = 0; o4 < 10; ++o4) acc[o4] = *(const float4*)&b2[o4 * 4];

    const float4* hr = (const float4*)(h + (size_t)n * HID);
    const float4* wt = (const float4*)W2T;
    for (int j = 0; j < HID / 4; ++j) {
        float4 hv = hr[j];
#pragma unroll
        for (int c = 0; c < 4; ++c) {
            float hk = (c == 0) ? hv.x : (c == 1) ? hv.y : (c == 2) ? hv.z : hv.w;
            const float4* wr = wt + (size_t)(j * 4 + c) * 10;
#pragma unroll
            for (int o4 = 0; o4 < 10; ++o4) {
                float4 w = wr[o4];
                acc[o4].x += hk * w.x;
                acc[o4].y += hk * w.y;
                acc[o4].z += hk * w.z;
                acc[o4].w += hk * w.w;
            }
        }
    }
    uint2* pp = (uint2*)(hbuf0 + (size_t)n * OUT_DIM);
#pragma unroll
    for (int o4 = 0; o4 < 10; ++o4) {
        uint2 w;
        w.x = (unsigned)bf16_rne(acc[o4].x) | ((unsigned)bf16_rne(acc[o4].y) << 16);
        w.y = (unsigned)bf16_rne(acc[o4].z) | ((unsigned)bf16_rne(acc[o4].w) << 16);
        pp[o4] = w;
    }
}

// ---------------- propagation steps 1..9: spmm5, writes bf16 h_k only ----------------
__global__ __launch_bounds__(256) void k_spmm5(const int* __restrict__ ptr,
                                               const unsigned* __restrict__ ep4,
                                               const unsigned short* __restrict__ cur,
                                               unsigned short* __restrict__ nxt) {
    int wave = (blockIdx.x * blockDim.x + threadIdx.x) >> 6;
    int lane = threadIdx.x & 63;
    if (wave >= NN) return;
    int e0 = ptr[wave], e1 = ptr[wave + 1];
    int es = lane / 10;            // 0..6 (6 => lanes 60-63 idle)
    int fq = lane - es * 10;       // 0..9
    bool act = es < 6;
    float a0 = 0.f, a1 = 0.f, a2 = 0.f, a3 = 0.f;

    for (int base = e0; base < e1; base += 48) {
        unsigned q[8];
#pragma unroll
        for (int g = 0; g < 8; ++g) {
            int e = base + g * 6 + es;
            q[g] = (act && e < e1) ? ep4[e] : 0u;
        }
#pragma unroll
        for (int g = 0; g < 8; ++g) {
            int src = (int)(q[g] & 0xFFFFu);
            float nm = f16_to_f32((unsigned short)(q[g] >> 16));
            uint2 u = *((const uint2*)(cur + (size_t)src * OUT_DIM) + fq);
            a0 += nm * __uint_as_float(u.x << 16);
            a1 += nm * __uint_as_float(u.x & 0xFFFF0000u);
            a2 += nm * __uint_as_float(u.y << 16);
            a3 += nm * __uint_as_float(u.y & 0xFFFF0000u);
        }
    }
    float s0 = a0, s1 = a1, s2 = a2, s3 = a3;
#pragma unroll
    for (int j = 1; j < 6; ++j) {
        s0 += __shfl(a0, fq + j * 10);
        s1 += __shfl(a1, fq + j * 10);
        s2 += __shfl(a2, fq + j * 10);
        s3 += __shfl(a3, fq + j * 10);
    }
    if (lane < 10) {
        uint2 w;
        w.x = (unsigned)bf16_rne(s0) | ((unsigned)bf16_rne(s1) << 16);
        w.y = (unsigned)bf16_rne(s2) | ((unsigned)bf16_rne(s3) << 16);
        *((uint2*)(nxt + (size_t)wave * OUT_DIM) + lane) = w;
    }
}

// ---------------- propagation step 10 fused with the gamma-weighted output sum ----------------
// Same gather body; instead of writing h_10, loads z and h_1..h_9 for this node
// (10 coalesced uint2 loads per lane<10) and writes out = sum_k gamma[k]*h_k.
__global__ __launch_bounds__(256) void k_spmm5f(const int* __restrict__ ptr,
                                                const unsigned* __restrict__ ep4,
                                                const unsigned short* __restrict__ cur,
                                                const unsigned short* __restrict__ hbuf0,
                                                const unsigned short* __restrict__ hchain,
                                                const float* __restrict__ gamma,
                                                float* __restrict__ out) {
    int wave = (blockIdx.x * blockDim.x + threadIdx.x) >> 6;
    int lane = threadIdx.x & 63;
    if (wave >= NN) return;
    int e0 = ptr[wave], e1 = ptr[wave + 1];
    int es = lane / 10;
    int fq = lane - es * 10;
    bool act = es < 6;
    float a0 = 0.f, a1 = 0.f, a2 = 0.f, a3 = 0.f;

    for (int base = e0; base < e1; base += 48) {
        unsigned q[8];
#pragma unroll
        for (int g = 0; g < 8; ++g) {
            int e = base + g * 6 + es;
            q[g] = (act && e < e1) ? ep4[e] : 0u;
        }
#pragma unroll
        for (int g = 0; g < 8; ++g) {
            int src = (int)(q[g] & 0xFFFFu);
            float nm = f16_to_f32((unsigned short)(q[g] >> 16));
            uint2 u = *((const uint2*)(cur + (size_t)src * OUT_DIM) + fq);
            a0 += nm * __uint_as_float(u.x << 16);
            a1 += nm * __uint_as_float(u.x & 0xFFFF0000u);
            a2 += nm * __uint_as_float(u.y << 16);
            a3 += nm * __uint_as_float(u.y & 0xFFFF0000u);
        }
    }
    float s0 = a0, s1 = a1, s2 = a2, s3 = a3;
#pragma unroll
    for (int j = 1; j < 6; ++j) {
        s0 += __shfl(a0, fq + j * 10);
        s1 += __shfl(a1, fq + j * 10);
        s2 += __shfl(a2, fq + j * 10);
        s3 += __shfl(a3, fq + j * 10);
    }
    if (lane < 10) {
        float gK = gamma[KSTEPS];
        float o0 = gK * s0, o1 = gK * s1, o2 = gK * s2, o3 = gK * s3;
        // + gamma0 * z
        {
            float g0 = gamma[0];
            uint2 u = *((const uint2*)(hbuf0 + (size_t)wave * OUT_DIM) + lane);
            o0 += g0 * __uint_as_float(u.x << 16);
            o1 += g0 * __uint_as_float(u.x & 0xFFFF0000u);
            o2 += g0 * __uint_as_float(u.y << 16);
            o3 += g0 * __uint_as_float(u.y & 0xFFFF0000u);
        }
#pragma unroll
        for (int k = 1; k < KSTEPS; ++k) {
            float gk = gamma[k];
            uint2 u = *((const uint2*)(hchain + (size_t)(k - 1) * NN * OUT_DIM
                                       + (size_t)wave * OUT_DIM) + lane);
            o0 += gk * __uint_as_float(u.x << 16);
            o1 += gk * __uint_as_float(u.x & 0xFFFF0000u);
            o2 += gk * __uint_as_float(u.y << 16);
            o3 += gk * __uint_as_float(u.y & 0xFFFF0000u);
        }
        *((float4*)(out + (size_t)wave * OUT_DIM) + lane) = make_float4(o0, o1, o2, o3);
    }
}

extern "C" void kernel_launch(void* const* d_in, const int* in_sizes, int n_in,
                              void* d_out, int out_size, void* d_ws, size_t ws_size,
                              hipStream_t stream) {
    const float* x   = (const float*)d_in[0];
    const int*   ei  = (const int*)d_in[1];
    const float* W1  = (const float*)d_in[2];
    const float* b1  = (const float*)d_in[3];
    const float* bnw = (const float*)d_in[4];
    const float* bnb = (const float*)d_in[5];
    const float* bnm = (const float*)d_in[6];
    const float* bnv = (const float*)d_in[7];
    const float* W2  = (const float*)d_in[8];
    const float* b2  = (const float*)d_in[9];
    const float* gamma = (const float*)d_in[10];
    float* out = (float*)d_out;

    char* ws = (char*)d_ws;
    const size_t A = 256;
    auto pad = [&](size_t b) { return (b + A - 1) / A * A; };
    size_t off = 0;
    int*      bptr  = (int*)     (ws + off); off += pad((size_t)(NB + 1) * 4);
    int*      totB  = (int*)     (ws + off); off += pad((size_t)NB * 4);
    float*    dinv  = (float*)   (ws + off); off += pad((size_t)NN * 4);
    int*      ptr   = (int*)     (ws + off); off += pad((size_t)(NN + 1) * 4);
    int2*     ep    = (int2*)    (ws + off); off += pad((size_t)EE * 8);   // build-only
    unsigned* ep4   = (unsigned*)(ws + off); off += pad((size_t)EE * 4);
    float*    h     = (float*)   (ws + off); off += pad((size_t)NN * HID * 4);
    unsigned short* hbuf0 = (unsigned short*)(ws + off); off += pad((size_t)NN * OUT_DIM * 2);
    unsigned short* w1h   = (unsigned short*)(ws + off); off += pad((size_t)HID * IN_DIM * 2);
    unsigned short* w1l   = (unsigned short*)(ws + off); off += pad((size_t)HID * IN_DIM * 2);

    // aliases into h:
    //  - hists: consumed by build BEFORE gemm1m writes h
    //  - hchain[0..8] (9 x 4 MB): written by spmm AFTER gemm2 consumed h
    unsigned* histR8 = (unsigned*)h;                              // 12.8 MB
    int* histBT = (int*)((char*)h + (size_t)HB * HRW * 4);        // 1.31 MB, [NB][HB]
    unsigned short* hchain = (unsigned short*)h;                  // 9 x NN*OUT_DIM bf16

    // graph build
    k_hist<<<HB, 256, 0, stream>>>(ei, histR8, histBT);
    k_aux<<<DINV_B + COL_B + W1_B, 256, 0, stream>>>(histR8, dinv, histBT, totB,
                                                     W1, w1h, w1l);
    k_scanT<<<1, 256, 0, stream>>>(totB, bptr);
    k_scatterB<<<HB, 256, 0, stream>>>(ei, dinv, bptr, histBT, ep);
    k_sortB<<<NB, 256, 0, stream>>>(bptr, ep, ep4, ptr);

    // MLP
    dim3 g1((NN + BM - 1) / BM, 2);
    k_gemm1m<<<g1, 256, 0, stream>>>(x, w1h, w1l, b1, bnw, bnb, bnm, bnv, h);
    k_gemm2<<<(NN + 255) / 256, 256, 0, stream>>>(h, W2, b2, hbuf0);

    // propagation: steps 1..9 write hchain; step 10 fused with gamma-sum -> out
    int grid = (NN * 64 + 255) / 256;
    for (int k = 1; k < KSTEPS; ++k) {
        const unsigned short* cur = (k == 1) ? hbuf0
                                             : hchain + (size_t)(k - 2) * NN * OUT_DIM;
        unsigned short* nxt = hchain + (size_t)(k - 1) * NN * OUT_DIM;
        k_spmm5<<<grid, 256, 0, stream>>>(ptr, ep4, cur, nxt);
    }
    k_spmm5f<<<grid, 256, 0, stream>>>(ptr, ep4,
                                       hchain + (size_t)(KSTEPS - 2) * NN * OUT_DIM,
                                       hbuf0, hchain, gamma, out);
}